// Round 1
// baseline (657.611 us; speedup 1.0000x reference)
//
#include <hip/hip_runtime.h>
#include <math.h>

#define P_N 524288
#define NFRAMES 100
#define RESO_ 256
#define CHAN_ 64
#define NFREQ 10

// Transposed layout: T[(f*3+pl)][t][x][c] ; c contiguous
#define TROW   (RESO_ * CHAN_)          // 16384 floats per t-row
#define TPLANE (NFRAMES * TROW)         // 1,638,400 floats per plane

__global__ __launch_bounds__(256) void transpose_k(const float* __restrict__ f0,
                                                   const float* __restrict__ f1,
                                                   const float* __restrict__ f2,
                                                   float* __restrict__ T) {
  __shared__ float tile[64][65];
  int b = blockIdx.x;
  int xblk = b & 3; b >>= 2;                 // 4 x-tiles of 64
  int t = b % NFRAMES; b /= NFRAMES;
  int pl = b % 3; int f = b / 3;
  const float* src = (f == 0 ? f0 : (f == 1 ? f1 : f2)) + (size_t)pl * CHAN_ * NFRAMES * RESO_;
  int lane = threadIdx.x & 63;
  int w = threadIdx.x >> 6;
  // read: lane = x offset (coalesced), rows = channels
  #pragma unroll
  for (int c = 0; c < 16; c++) {
    int cc = w * 16 + c;
    tile[cc][lane] = src[(size_t)cc * (NFRAMES * RESO_) + (size_t)t * RESO_ + xblk * 64 + lane];
  }
  __syncthreads();
  // write: lane = channel (coalesced)
  float* dst = T + ((size_t)(f * 3 + pl) * NFRAMES + t) * TROW + (size_t)(xblk * 64) * CHAN_;
  #pragma unroll
  for (int i = 0; i < 16; i++) {
    int xx = w * 16 + i;
    dst[(size_t)xx * CHAN_ + lane] = tile[lane][xx];
  }
}

template <bool TRANS>
__global__ __launch_bounds__(256) void sample_k(const float* __restrict__ xin,
                                                const float* __restrict__ T,
                                                const float* __restrict__ f0,
                                                const float* __restrict__ f1,
                                                const float* __restrict__ f2,
                                                float* __restrict__ out) {
  const int lane = threadIdx.x & 63;
  int wave = blockIdx.x * 4 + (threadIdx.x >> 6);
  const int nW = gridDim.x * 4;
  for (int p = wave; p < P_N; p += nW) {
    float cx = xin[(size_t)p * 4 + 0];
    float cy = xin[(size_t)p * 4 + 1];
    float cz = xin[(size_t)p * 4 + 2];
    float ct = xin[(size_t)p * 4 + 3];

    // exactly the reference's op order
    float tn = ct / 99.0f;                       // t / (NUM_FRAMES-1)
    float gy = 2.0f * tn - 1.0f;
    float iy = ((gy + 1.0f) * 0.5f) * 99.0f;     // (gy+1)*0.5*(H-1)
    float y0f = floorf(iy);
    float wy1 = iy - y0f;
    float wy0 = 1.0f - wy1;
    int y0 = (int)y0f;
    int y1 = y0 + 1;
    bool y0in = (unsigned)y0 < (unsigned)NFRAMES;
    bool y1in = (unsigned)y1 < (unsigned)NFRAMES;
    int y0c = min(max(y0, 0), NFRAMES - 1);
    int y1c = min(max(y1, 0), NFRAMES - 1);

    float delta0 = 0.0f, delta1 = 0.0f, delta2 = 0.0f;
    #pragma unroll
    for (int f = 0; f < 3; f++) {
      float prodc = 0.0f;
      #pragma unroll
      for (int pl = 0; pl < 3; pl++) {
        float coord = (pl == 0) ? cx : (pl == 1) ? cy : cz;
        float gx = 2.0f * coord - 1.0f;
        float ix = ((gx + 1.0f) * 0.5f) * 255.0f; // (gx+1)*0.5*(W-1)
        float x0f = floorf(ix);
        float wx1 = ix - x0f;
        float wx0 = 1.0f - wx1;
        int x0 = (int)x0f;
        int x1 = x0 + 1;
        bool x0in = (unsigned)x0 < (unsigned)RESO_;
        bool x1in = (unsigned)x1 < (unsigned)RESO_;
        int x0c = min(max(x0, 0), RESO_ - 1);
        int x1c = min(max(x1, 0), RESO_ - 1);

        float v00, v01, v10, v11;
        if (TRANS) {
          const float* base = T + (size_t)(f * 3 + pl) * TPLANE;
          const float* r0 = base + (size_t)y0c * TROW;
          const float* r1 = base + (size_t)y1c * TROW;
          v00 = (y0in && x0in) ? r0[x0c * CHAN_ + lane] : 0.0f;
          v01 = (y0in && x1in) ? r0[x1c * CHAN_ + lane] : 0.0f;
          v10 = (y1in && x0in) ? r1[x0c * CHAN_ + lane] : 0.0f;
          v11 = (y1in && x1in) ? r1[x1c * CHAN_ + lane] : 0.0f;
        } else {
          const float* ff = (f == 0) ? f0 : (f == 1) ? f1 : f2;
          const float* base = ff + ((size_t)pl * CHAN_ + lane) * (NFRAMES * RESO_);
          v00 = (y0in && x0in) ? base[(size_t)y0c * RESO_ + x0c] : 0.0f;
          v01 = (y0in && x1in) ? base[(size_t)y0c * RESO_ + x1c] : 0.0f;
          v10 = (y1in && x0in) ? base[(size_t)y1c * RESO_ + x0c] : 0.0f;
          v11 = (y1in && x1in) ? base[(size_t)y1c * RESO_ + x1c] : 0.0f;
        }
        float s = v00 * (wy0 * wx0) + v01 * (wy0 * wx1) + v10 * (wy1 * wx0) + v11 * (wy1 * wx1);
        prodc = (pl == 0) ? s : prodc * s;
      }
      // sum over 64 channels (lanes)
      float sum = prodc;
      #pragma unroll
      for (int o = 32; o > 0; o >>= 1) sum += __shfl_xor(sum, o, 64);
      if (f == 0) delta0 = sum;
      else if (f == 1) delta1 = sum;
      else delta2 = sum;
    }

    float p0 = cx + delta0;
    float p1 = cy + delta1;
    float p2 = cz + delta2;

    if (lane < 63) {
      float val;
      if (lane == 0) val = p0;
      else if (lane == 1) val = p1;
      else if (lane == 2) val = p2;
      else {
        int j = lane - 3;
        int fq = j / 6;
        int r = j - fq * 6;
        int s = r / 3;
        int d = r - s * 3;
        float pd = (d == 0) ? p0 : (d == 1) ? p1 : p2;
        float ang = pd * (float)(1 << fq);   // exact pow2 multiply
        val = (s == 0) ? sinf(ang) : cosf(ang);
      }
      out[(size_t)p * 63 + lane] = val;
    }
  }
}

extern "C" void kernel_launch(void* const* d_in, const int* in_sizes, int n_in,
                              void* d_out, int out_size, void* d_ws, size_t ws_size,
                              hipStream_t stream) {
  const float* x  = (const float*)d_in[0];
  const float* f0 = (const float*)d_in[1];
  const float* f1 = (const float*)d_in[2];
  const float* f2 = (const float*)d_in[3];
  float* out = (float*)d_out;

  size_t needT = (size_t)9 * TPLANE * sizeof(float);   // ~59 MB
  if (ws_size >= needT) {
    float* T = (float*)d_ws;
    transpose_k<<<dim3(3 * 3 * NFRAMES * 4), dim3(256), 0, stream>>>(f0, f1, f2, T);
    sample_k<true><<<dim3(8192), dim3(256), 0, stream>>>(x, T, f0, f1, f2, out);
  } else {
    sample_k<false><<<dim3(8192), dim3(256), 0, stream>>>(x, nullptr, f0, f1, f2, out);
  }
}

// Round 2
// 346.542 us; speedup vs baseline: 1.8976x; 1.8976x over previous
//
#include <hip/hip_runtime.h>
#include <math.h>

#define P_N 524288
#define NFRAMES 100
#define RESO_ 256
#define CHAN_ 64
#define NFREQ 10

// Transposed layout: T[(f*3+pl)][t][x][c] ; c contiguous
#define TROW   (RESO_ * CHAN_)          // 16384 floats per t-row
#define TPLANE (NFRAMES * TROW)         // 1,638,400 floats per plane

__global__ __launch_bounds__(256) void transpose_k(const float* __restrict__ f0,
                                                   const float* __restrict__ f1,
                                                   const float* __restrict__ f2,
                                                   float* __restrict__ T) {
  __shared__ float tile[64][65];
  int b = blockIdx.x;
  int xblk = b & 3; b >>= 2;                 // 4 x-tiles of 64
  int t = b % NFRAMES; b /= NFRAMES;
  int pl = b % 3; int f = b / 3;
  const float* src = (f == 0 ? f0 : (f == 1 ? f1 : f2)) + (size_t)pl * CHAN_ * NFRAMES * RESO_;
  int lane = threadIdx.x & 63;
  int w = threadIdx.x >> 6;
  #pragma unroll
  for (int c = 0; c < 16; c++) {
    int cc = w * 16 + c;
    tile[cc][lane] = src[(size_t)cc * (NFRAMES * RESO_) + (size_t)t * RESO_ + xblk * 64 + lane];
  }
  __syncthreads();
  float* dst = T + ((size_t)(f * 3 + pl) * NFRAMES + t) * TROW + (size_t)(xblk * 64) * CHAN_;
  #pragma unroll
  for (int i = 0; i < 16; i++) {
    int xx = w * 16 + i;
    dst[(size_t)xx * CHAN_ + lane] = tile[lane][xx];
  }
}

__device__ __forceinline__ float hw_sin_rev(float rev) {
  // returns sin(2*pi*rev); rev any float, fract applied here
  float r = rev - floorf(rev);
  float s;
  asm("v_sin_f32 %0, %1" : "=v"(s) : "v"(r));
  return s;
}

// 2 points per wave: lanes 0-31 -> point base+0, lanes 32-63 -> point base+1.
// Each lane holds channels (2l, 2l+1) as float2.
__global__ __launch_bounds__(256) void sample2_k(const float* __restrict__ xin,
                                                 const float* __restrict__ T,
                                                 float* __restrict__ out) {
  const int lane = threadIdx.x & 63;
  const int half = lane >> 5;
  const int l = lane & 31;
  const int wave = blockIdx.x * 4 + (threadIdx.x >> 6);
  const int nW = gridDim.x * 4;

  // per-lane output-element constants (element id = lane, valid for lane<63)
  const int j = (lane >= 3) ? (lane - 3) : 0;
  const int fq = j / 6;
  const int rr = j - fq * 6;
  const int isc = rr / 3;          // 0=sin, 1=cos
  const int dd = rr - isc * 3;     // which of p0/p1/p2
  const float scale = (float)(1 << fq);
  const float cosoff = isc ? 0.25f : 0.0f;
  const float inv2pi = 0.15915493667125702f;

  const float4* __restrict__ x4 = (const float4*)xin;

  for (int base = wave * 2; base < P_N; base += nW * 2) {
    const int p = base + half;
    float4 c = x4[p];

    // ---- t-axis: reference op order; pick dominant row (eps-row dropped) ----
    float tn = c.w / 99.0f;
    float gy = 2.0f * tn - 1.0f;
    float iy = ((gy + 1.0f) * 0.5f) * 99.0f;
    float y0f = floorf(iy);
    float wy1 = iy - y0f;
    int row; float wy;
    if (wy1 > 0.5f) { row = (int)y0f + 1; wy = wy1; }
    else            { row = (int)y0f;     wy = 1.0f - wy1; }
    row = min(max(row, 0), NFRAMES - 1);
    const int rowoff = row * TROW;

    // ---- 9 plane samples ----
    float dsum[3];
    float coords[3] = {c.x, c.y, c.z};
    #pragma unroll
    for (int f = 0; f < 3; f++) {
      float prx, pry;
      #pragma unroll
      for (int pl = 0; pl < 3; pl++) {
        float gx = 2.0f * coords[pl] - 1.0f;
        float ix = ((gx + 1.0f) * 0.5f) * 255.0f;
        float x0f = floorf(ix);
        float wx1 = ix - x0f;
        float wx0 = 1.0f - wx1;
        int x0 = (int)x0f;                     // in [0,254] (coords uniform [0,1))
        const float2* rp = (const float2*)(T + (size_t)(f * 3 + pl) * TPLANE
                                             + (size_t)(rowoff + x0 * CHAN_));
        float2 v0 = rp[l];            // channels 2l,2l+1 at x0
        float2 v1 = rp[l + 32];       // channels 2l,2l+1 at x0+1
        float sx = (v0.x * wx0 + v1.x * wx1) * wy;
        float sy = (v0.y * wx0 + v1.y * wx1) * wy;
        if (pl == 0) { prx = sx; pry = sy; }
        else         { prx *= sx; pry *= sy; }
      }
      float r = prx + pry;
      #pragma unroll
      for (int m = 16; m > 0; m >>= 1) r += __shfl_xor(r, m, 64);  // within 32-half
      dsum[f] = r;
    }

    float px = c.x + dsum[0];
    float py = c.y + dsum[1];
    float pz = c.z + dsum[2];

    // ---- outputs: 63 floats per point, two passes (one per half's point) ----
    #pragma unroll
    for (int q = 0; q < 2; q++) {
      float qx = __shfl(px, q * 32, 64);
      float qy = __shfl(py, q * 32, 64);
      float qz = __shfl(pz, q * 32, 64);
      float pd = (dd == 0) ? qx : (dd == 1) ? qy : qz;
      float ang = pd * scale;
      float val = hw_sin_rev(ang * inv2pi + cosoff);
      if (lane == 0) val = qx;
      else if (lane == 1) val = qy;
      else if (lane == 2) val = qz;
      if (lane < 63) out[(size_t)(base + q) * 63 + lane] = val;
    }
  }
}

// ---- fallback (ws too small): round-1 style direct-layout sampler ----
__global__ __launch_bounds__(256) void sample_fb_k(const float* __restrict__ xin,
                                                   const float* __restrict__ f0,
                                                   const float* __restrict__ f1,
                                                   const float* __restrict__ f2,
                                                   float* __restrict__ out) {
  const int lane = threadIdx.x & 63;
  int wave = blockIdx.x * 4 + (threadIdx.x >> 6);
  const int nW = gridDim.x * 4;
  for (int p = wave; p < P_N; p += nW) {
    float cx = xin[(size_t)p * 4 + 0];
    float cy = xin[(size_t)p * 4 + 1];
    float cz = xin[(size_t)p * 4 + 2];
    float ct = xin[(size_t)p * 4 + 3];
    float tn = ct / 99.0f;
    float gy = 2.0f * tn - 1.0f;
    float iy = ((gy + 1.0f) * 0.5f) * 99.0f;
    float y0f = floorf(iy);
    float wy1 = iy - y0f;
    float wy0 = 1.0f - wy1;
    int y0 = (int)y0f, y1 = y0 + 1;
    bool y0in = (unsigned)y0 < (unsigned)NFRAMES;
    bool y1in = (unsigned)y1 < (unsigned)NFRAMES;
    int y0c = min(max(y0, 0), NFRAMES - 1);
    int y1c = min(max(y1, 0), NFRAMES - 1);
    float d[3];
    #pragma unroll
    for (int f = 0; f < 3; f++) {
      float prodc;
      #pragma unroll
      for (int pl = 0; pl < 3; pl++) {
        float coord = (pl == 0) ? cx : (pl == 1) ? cy : cz;
        float gx = 2.0f * coord - 1.0f;
        float ix = ((gx + 1.0f) * 0.5f) * 255.0f;
        float x0f = floorf(ix);
        float wx1 = ix - x0f;
        float wx0 = 1.0f - wx1;
        int x0 = (int)x0f, x1 = x0 + 1;
        int x0c = min(max(x0, 0), RESO_ - 1);
        int x1c = min(max(x1, 0), RESO_ - 1);
        const float* ff = (f == 0) ? f0 : (f == 1) ? f1 : f2;
        const float* bse = ff + ((size_t)pl * CHAN_ + lane) * (NFRAMES * RESO_);
        float v00 = y0in ? bse[(size_t)y0c * RESO_ + x0c] : 0.0f;
        float v01 = y0in ? bse[(size_t)y0c * RESO_ + x1c] : 0.0f;
        float v10 = y1in ? bse[(size_t)y1c * RESO_ + x0c] : 0.0f;
        float v11 = y1in ? bse[(size_t)y1c * RESO_ + x1c] : 0.0f;
        float s = v00 * (wy0 * wx0) + v01 * (wy0 * wx1) + v10 * (wy1 * wx0) + v11 * (wy1 * wx1);
        prodc = (pl == 0) ? s : prodc * s;
      }
      float sum = prodc;
      #pragma unroll
      for (int o = 32; o > 0; o >>= 1) sum += __shfl_xor(sum, o, 64);
      d[f] = sum;
    }
    float p0 = cx + d[0], p1 = cy + d[1], p2 = cz + d[2];
    if (lane < 63) {
      float val;
      if (lane == 0) val = p0;
      else if (lane == 1) val = p1;
      else if (lane == 2) val = p2;
      else {
        int jj = lane - 3;
        int fq2 = jj / 6;
        int r2 = jj - fq2 * 6;
        int s2 = r2 / 3;
        int d2 = r2 - s2 * 3;
        float pd = (d2 == 0) ? p0 : (d2 == 1) ? p1 : p2;
        float ang = pd * (float)(1 << fq2);
        val = (s2 == 0) ? sinf(ang) : cosf(ang);
      }
      out[(size_t)p * 63 + lane] = val;
    }
  }
}

extern "C" void kernel_launch(void* const* d_in, const int* in_sizes, int n_in,
                              void* d_out, int out_size, void* d_ws, size_t ws_size,
                              hipStream_t stream) {
  const float* x  = (const float*)d_in[0];
  const float* f0 = (const float*)d_in[1];
  const float* f1 = (const float*)d_in[2];
  const float* f2 = (const float*)d_in[3];
  float* out = (float*)d_out;

  size_t needT = (size_t)9 * TPLANE * sizeof(float);   // ~59 MB
  if (ws_size >= needT) {
    float* T = (float*)d_ws;
    transpose_k<<<dim3(3 * 3 * NFRAMES * 4), dim3(256), 0, stream>>>(f0, f1, f2, T);
    sample2_k<<<dim3(4096), dim3(256), 0, stream>>>(x, T, out);
  } else {
    sample_fb_k<<<dim3(8192), dim3(256), 0, stream>>>(x, f0, f1, f2, out);
  }
}

// Round 3
// 285.820 us; speedup vs baseline: 2.3008x; 1.2124x over previous
//
#include <hip/hip_runtime.h>
#include <math.h>

#define P_N 524288
#define NFRAMES 100
#define RESO_ 256
#define CHAN_ 64
#define NFREQ 10

// Transposed layout: T[(f*3+pl)][t][x][c] ; c contiguous
#define TROW   (RESO_ * CHAN_)          // 16384 floats per t-row
#define TPLANE (NFRAMES * TROW)         // 1,638,400 floats per plane

#define NSUB 64
#define NBIN (NFRAMES * NSUB)           // 6400 buckets: key = t*64 + (p>>13)

__global__ __launch_bounds__(256) void transpose_k(const float* __restrict__ f0,
                                                   const float* __restrict__ f1,
                                                   const float* __restrict__ f2,
                                                   float* __restrict__ T) {
  __shared__ float tile[64][65];
  int b = blockIdx.x;
  int xblk = b & 3; b >>= 2;                 // 4 x-tiles of 64
  int t = b % NFRAMES; b /= NFRAMES;
  int pl = b % 3; int f = b / 3;
  const float* src = (f == 0 ? f0 : (f == 1 ? f1 : f2)) + (size_t)pl * CHAN_ * NFRAMES * RESO_;
  int lane = threadIdx.x & 63;
  int w = threadIdx.x >> 6;
  #pragma unroll
  for (int c = 0; c < 16; c++) {
    int cc = w * 16 + c;
    tile[cc][lane] = src[(size_t)cc * (NFRAMES * RESO_) + (size_t)t * RESO_ + xblk * 64 + lane];
  }
  __syncthreads();
  float* dst = T + ((size_t)(f * 3 + pl) * NFRAMES + t) * TROW + (size_t)(xblk * 64) * CHAN_;
  #pragma unroll
  for (int i = 0; i < 16; i++) {
    int xx = w * 16 + i;
    dst[(size_t)xx * CHAN_ + lane] = tile[lane][xx];
  }
}

// ---------------- counting sort by t ----------------
__global__ __launch_bounds__(256) void zero_k(int* __restrict__ bins) {
  for (int i = threadIdx.x; i < NBIN; i += 256) bins[i] = 0;
}

__device__ __forceinline__ int point_key(const float* xin, int p) {
  float ct = xin[(size_t)p * 4 + 3];
  int t = (int)ct;
  t = min(max(t, 0), NFRAMES - 1);
  return t * NSUB + (p >> 13);
}

__global__ __launch_bounds__(256) void hist_k(const float* __restrict__ xin,
                                              int* __restrict__ bins) {
  int p = blockIdx.x * 256 + threadIdx.x;
  if (p < P_N) atomicAdd(&bins[point_key(xin, p)], 1);
}

__global__ __launch_bounds__(256) void scan_k(const int* __restrict__ bins,
                                              int* __restrict__ cursors) {
  __shared__ int part[256];
  const int tid = threadIdx.x;
  const int CHUNK = NBIN / 256;          // 25
  int loc[CHUNK];
  int s = 0;
  #pragma unroll
  for (int i = 0; i < CHUNK; i++) { loc[i] = s; s += bins[tid * CHUNK + i]; }
  part[tid] = s;
  __syncthreads();
  if (tid == 0) {
    int r = 0;
    for (int j = 0; j < 256; j++) { int v = part[j]; part[j] = r; r += v; }
  }
  __syncthreads();
  #pragma unroll
  for (int i = 0; i < CHUNK; i++) cursors[tid * CHUNK + i] = part[tid] + loc[i];
}

__global__ __launch_bounds__(256) void scatter_k(const float* __restrict__ xin,
                                                 int* __restrict__ cursors,
                                                 int* __restrict__ perm) {
  int p = blockIdx.x * 256 + threadIdx.x;
  if (p < P_N) {
    int pos = atomicAdd(&cursors[point_key(xin, p)], 1);
    perm[pos] = p;
  }
}

// ---------------- sampler ----------------
__device__ __forceinline__ float hw_sin_rev(float rev) {
  float r = rev - floorf(rev);
  float s;
  asm("v_sin_f32 %0, %1" : "=v"(s) : "v"(r));
  return s;
}

// 2 points per wave iteration: lanes 0-31 -> point i, lanes 32-63 -> point i+1.
// Each lane holds channels (2l, 2l+1) as float2. Waves own CONTIGUOUS 32-point
// runs of the t-sorted order; XCD-swizzled block id keeps a t-bin on one XCD.
__global__ __launch_bounds__(256) void sample_sorted_k(const float* __restrict__ xin,
                                                       const float* __restrict__ T,
                                                       const int* __restrict__ perm,
                                                       float* __restrict__ out) {
  const int lane = threadIdx.x & 63;
  const int half = lane >> 5;
  const int l = lane & 31;
  const int b = blockIdx.x;
  const int swz = (b & 7) * (4096 / 8) + (b >> 3);   // XCD-contiguous
  const int wave = swz * 4 + (threadIdx.x >> 6);
  const int base0 = wave * 32;                        // 16384 waves * 32 = P_N

  const int j = (lane >= 3) ? (lane - 3) : 0;
  const int fq = j / 6;
  const int rr = j - fq * 6;
  const int isc = rr / 3;
  const int dd = rr - isc * 3;
  const float scale = (float)(1 << fq);
  const float cosoff = isc ? 0.25f : 0.0f;
  const float inv2pi = 0.15915493667125702f;

  const float4* __restrict__ x4 = (const float4*)xin;

  for (int i = base0; i < base0 + 32; i += 2) {
    const int p = perm[i + half];
    float4 c = x4[p];

    // t-axis: reference op order; dominant row (eps-row dropped)
    float tn = c.w / 99.0f;
    float gy = 2.0f * tn - 1.0f;
    float iy = ((gy + 1.0f) * 0.5f) * 99.0f;
    float y0f = floorf(iy);
    float wy1 = iy - y0f;
    int row; float wy;
    if (wy1 > 0.5f) { row = (int)y0f + 1; wy = wy1; }
    else            { row = (int)y0f;     wy = 1.0f - wy1; }
    row = min(max(row, 0), NFRAMES - 1);
    const int rowoff = row * TROW;

    float dsum[3];
    float coords[3] = {c.x, c.y, c.z};
    #pragma unroll
    for (int f = 0; f < 3; f++) {
      float prx, pry;
      #pragma unroll
      for (int pl = 0; pl < 3; pl++) {
        float gx = 2.0f * coords[pl] - 1.0f;
        float ix = ((gx + 1.0f) * 0.5f) * 255.0f;
        float x0f = floorf(ix);
        float wx1 = ix - x0f;
        float wx0 = 1.0f - wx1;
        int x0 = (int)x0f;                 // coords uniform [0,1) -> in-bounds
        const float2* rp = (const float2*)(T + (size_t)(f * 3 + pl) * TPLANE
                                             + (size_t)(rowoff + x0 * CHAN_));
        float2 v0 = rp[l];
        float2 v1 = rp[l + 32];
        float sx = (v0.x * wx0 + v1.x * wx1) * wy;
        float sy = (v0.y * wx0 + v1.y * wx1) * wy;
        if (pl == 0) { prx = sx; pry = sy; }
        else         { prx *= sx; pry *= sy; }
      }
      float r = prx + pry;
      #pragma unroll
      for (int m = 16; m > 0; m >>= 1) r += __shfl_xor(r, m, 64);
      dsum[f] = r;
    }

    float px = c.x + dsum[0];
    float py = c.y + dsum[1];
    float pz = c.z + dsum[2];

    #pragma unroll
    for (int q = 0; q < 2; q++) {
      float qx = __shfl(px, q * 32, 64);
      float qy = __shfl(py, q * 32, 64);
      float qz = __shfl(pz, q * 32, 64);
      int pq = __shfl(p, q * 32, 64);
      float pd = (dd == 0) ? qx : (dd == 1) ? qy : qz;
      float ang = pd * scale;
      float val = hw_sin_rev(ang * inv2pi + cosoff);
      if (lane == 0) val = qx;
      else if (lane == 1) val = qy;
      else if (lane == 2) val = qz;
      if (lane < 63) out[(size_t)pq * 63 + lane] = val;
    }
  }
}

// unsorted variant (ws fits T only)
__global__ __launch_bounds__(256) void sample2_k(const float* __restrict__ xin,
                                                 const float* __restrict__ T,
                                                 float* __restrict__ out) {
  const int lane = threadIdx.x & 63;
  const int half = lane >> 5;
  const int l = lane & 31;
  const int wave = blockIdx.x * 4 + (threadIdx.x >> 6);
  const int nW = gridDim.x * 4;
  const int j = (lane >= 3) ? (lane - 3) : 0;
  const int fq = j / 6;
  const int rr = j - fq * 6;
  const int isc = rr / 3;
  const int dd = rr - isc * 3;
  const float scale = (float)(1 << fq);
  const float cosoff = isc ? 0.25f : 0.0f;
  const float inv2pi = 0.15915493667125702f;
  const float4* __restrict__ x4 = (const float4*)xin;

  for (int base = wave * 2; base < P_N; base += nW * 2) {
    const int p = base + half;
    float4 c = x4[p];
    float tn = c.w / 99.0f;
    float gy = 2.0f * tn - 1.0f;
    float iy = ((gy + 1.0f) * 0.5f) * 99.0f;
    float y0f = floorf(iy);
    float wy1 = iy - y0f;
    int row; float wy;
    if (wy1 > 0.5f) { row = (int)y0f + 1; wy = wy1; }
    else            { row = (int)y0f;     wy = 1.0f - wy1; }
    row = min(max(row, 0), NFRAMES - 1);
    const int rowoff = row * TROW;
    float dsum[3];
    float coords[3] = {c.x, c.y, c.z};
    #pragma unroll
    for (int f = 0; f < 3; f++) {
      float prx, pry;
      #pragma unroll
      for (int pl = 0; pl < 3; pl++) {
        float gx = 2.0f * coords[pl] - 1.0f;
        float ix = ((gx + 1.0f) * 0.5f) * 255.0f;
        float x0f = floorf(ix);
        float wx1 = ix - x0f;
        float wx0 = 1.0f - wx1;
        int x0 = (int)x0f;
        const float2* rp = (const float2*)(T + (size_t)(f * 3 + pl) * TPLANE
                                             + (size_t)(rowoff + x0 * CHAN_));
        float2 v0 = rp[l];
        float2 v1 = rp[l + 32];
        float sx = (v0.x * wx0 + v1.x * wx1) * wy;
        float sy = (v0.y * wx0 + v1.y * wx1) * wy;
        if (pl == 0) { prx = sx; pry = sy; }
        else         { prx *= sx; pry *= sy; }
      }
      float r = prx + pry;
      #pragma unroll
      for (int m = 16; m > 0; m >>= 1) r += __shfl_xor(r, m, 64);
      dsum[f] = r;
    }
    float px = c.x + dsum[0];
    float py = c.y + dsum[1];
    float pz = c.z + dsum[2];
    #pragma unroll
    for (int q = 0; q < 2; q++) {
      float qx = __shfl(px, q * 32, 64);
      float qy = __shfl(py, q * 32, 64);
      float qz = __shfl(pz, q * 32, 64);
      float pd = (dd == 0) ? qx : (dd == 1) ? qy : qz;
      float ang = pd * scale;
      float val = hw_sin_rev(ang * inv2pi + cosoff);
      if (lane == 0) val = qx;
      else if (lane == 1) val = qy;
      else if (lane == 2) val = qz;
      if (lane < 63) out[(size_t)(base + q) * 63 + lane] = val;
    }
  }
}

// ---- fallback (no usable ws): direct-layout sampler ----
__global__ __launch_bounds__(256) void sample_fb_k(const float* __restrict__ xin,
                                                   const float* __restrict__ f0,
                                                   const float* __restrict__ f1,
                                                   const float* __restrict__ f2,
                                                   float* __restrict__ out) {
  const int lane = threadIdx.x & 63;
  int wave = blockIdx.x * 4 + (threadIdx.x >> 6);
  const int nW = gridDim.x * 4;
  for (int p = wave; p < P_N; p += nW) {
    float cx = xin[(size_t)p * 4 + 0];
    float cy = xin[(size_t)p * 4 + 1];
    float cz = xin[(size_t)p * 4 + 2];
    float ct = xin[(size_t)p * 4 + 3];
    float tn = ct / 99.0f;
    float gy = 2.0f * tn - 1.0f;
    float iy = ((gy + 1.0f) * 0.5f) * 99.0f;
    float y0f = floorf(iy);
    float wy1 = iy - y0f;
    float wy0 = 1.0f - wy1;
    int y0 = (int)y0f, y1 = y0 + 1;
    bool y0in = (unsigned)y0 < (unsigned)NFRAMES;
    bool y1in = (unsigned)y1 < (unsigned)NFRAMES;
    int y0c = min(max(y0, 0), NFRAMES - 1);
    int y1c = min(max(y1, 0), NFRAMES - 1);
    float d[3];
    #pragma unroll
    for (int f = 0; f < 3; f++) {
      float prodc;
      #pragma unroll
      for (int pl = 0; pl < 3; pl++) {
        float coord = (pl == 0) ? cx : (pl == 1) ? cy : cz;
        float gx = 2.0f * coord - 1.0f;
        float ix = ((gx + 1.0f) * 0.5f) * 255.0f;
        float x0f = floorf(ix);
        float wx1 = ix - x0f;
        float wx0 = 1.0f - wx1;
        int x0 = (int)x0f, x1 = x0 + 1;
        int x0c = min(max(x0, 0), RESO_ - 1);
        int x1c = min(max(x1, 0), RESO_ - 1);
        const float* ff = (f == 0) ? f0 : (f == 1) ? f1 : f2;
        const float* bse = ff + ((size_t)pl * CHAN_ + lane) * (NFRAMES * RESO_);
        float v00 = y0in ? bse[(size_t)y0c * RESO_ + x0c] : 0.0f;
        float v01 = y0in ? bse[(size_t)y0c * RESO_ + x1c] : 0.0f;
        float v10 = y1in ? bse[(size_t)y1c * RESO_ + x0c] : 0.0f;
        float v11 = y1in ? bse[(size_t)y1c * RESO_ + x1c] : 0.0f;
        float s = v00 * (wy0 * wx0) + v01 * (wy0 * wx1) + v10 * (wy1 * wx0) + v11 * (wy1 * wx1);
        prodc = (pl == 0) ? s : prodc * s;
      }
      float sum = prodc;
      #pragma unroll
      for (int o = 32; o > 0; o >>= 1) sum += __shfl_xor(sum, o, 64);
      d[f] = sum;
    }
    float p0 = cx + d[0], p1 = cy + d[1], p2 = cz + d[2];
    if (lane < 63) {
      float val;
      if (lane == 0) val = p0;
      else if (lane == 1) val = p1;
      else if (lane == 2) val = p2;
      else {
        int jj = lane - 3;
        int fq2 = jj / 6;
        int r2 = jj - fq2 * 6;
        int s2 = r2 / 3;
        int d2 = r2 - s2 * 3;
        float pd = (d2 == 0) ? p0 : (d2 == 1) ? p1 : p2;
        float ang = pd * (float)(1 << fq2);
        val = (s2 == 0) ? sinf(ang) : cosf(ang);
      }
      out[(size_t)p * 63 + lane] = val;
    }
  }
}

extern "C" void kernel_launch(void* const* d_in, const int* in_sizes, int n_in,
                              void* d_out, int out_size, void* d_ws, size_t ws_size,
                              hipStream_t stream) {
  const float* x  = (const float*)d_in[0];
  const float* f0 = (const float*)d_in[1];
  const float* f1 = (const float*)d_in[2];
  const float* f2 = (const float*)d_in[3];
  float* out = (float*)d_out;

  const size_t szT    = (size_t)9 * TPLANE * sizeof(float);     // ~59 MB
  const size_t szBins = (size_t)NBIN * sizeof(int);             // 25.6 KB
  const size_t szPerm = (size_t)P_N * sizeof(int);              // 2 MB
  const size_t needSorted = szT + 2 * szBins + szPerm;

  if (ws_size >= needSorted) {
    float* T      = (float*)d_ws;
    int* bins     = (int*)((char*)d_ws + szT);
    int* cursors  = (int*)((char*)d_ws + szT + szBins);
    int* perm     = (int*)((char*)d_ws + szT + 2 * szBins);
    transpose_k<<<dim3(3 * 3 * NFRAMES * 4), dim3(256), 0, stream>>>(f0, f1, f2, T);
    zero_k<<<dim3(1), dim3(256), 0, stream>>>(bins);
    hist_k<<<dim3(P_N / 256), dim3(256), 0, stream>>>(x, bins);
    scan_k<<<dim3(1), dim3(256), 0, stream>>>(bins, cursors);
    scatter_k<<<dim3(P_N / 256), dim3(256), 0, stream>>>(x, cursors, perm);
    sample_sorted_k<<<dim3(4096), dim3(256), 0, stream>>>(x, T, perm, out);
  } else if (ws_size >= szT) {
    float* T = (float*)d_ws;
    transpose_k<<<dim3(3 * 3 * NFRAMES * 4), dim3(256), 0, stream>>>(f0, f1, f2, T);
    sample2_k<<<dim3(4096), dim3(256), 0, stream>>>(x, T, out);
  } else {
    sample_fb_k<<<dim3(8192), dim3(256), 0, stream>>>(x, f0, f1, f2, out);
  }
}

// Round 4
// 258.114 us; speedup vs baseline: 2.5478x; 1.1073x over previous
//
#include <hip/hip_runtime.h>
#include <math.h>

#define P_N 524288
#define NFRAMES 100
#define RESO_ 256
#define CHAN_ 64
#define NFREQ 10

// Transposed layout: T[(f*3+pl)][t][x][c] ; c contiguous
#define TROW   (RESO_ * CHAN_)          // 16384 floats per t-row
#define TPLANE (NFRAMES * TROW)         // 1,638,400 floats per plane

#define NSUB 64
#define NBIN (NFRAMES * NSUB)           // 6400 buckets: key = t*64 + (p>>13)
#define NTRB (3 * 3 * NFRAMES * 4)      // 3600 transpose blocks
#define NHSB (P_N / 256)                // 2048 hist/scatter blocks

__device__ __forceinline__ int point_key(const float* xin, int p) {
  float ct = xin[(size_t)p * 4 + 3];
  int t = (int)ct;
  t = min(max(t, 0), NFRAMES - 1);
  return t * NSUB + (p >> 13);
}

// fused: blocks [0,NTRB) transpose features; blocks [NTRB, NTRB+NHSB) histogram
__global__ __launch_bounds__(256) void prep_k(const float* __restrict__ f0,
                                              const float* __restrict__ f1,
                                              const float* __restrict__ f2,
                                              float* __restrict__ T,
                                              const float* __restrict__ xin,
                                              int* __restrict__ bins) {
  if (blockIdx.x >= NTRB) {
    int p = (blockIdx.x - NTRB) * 256 + threadIdx.x;
    if (p < P_N) atomicAdd(&bins[point_key(xin, p)], 1);
    return;
  }
  __shared__ float tile[64][65];
  int b = blockIdx.x;
  int xblk = b & 3; b >>= 2;                 // 4 x-tiles of 64
  int t = b % NFRAMES; b /= NFRAMES;
  int pl = b % 3; int f = b / 3;
  const float* src = (f == 0 ? f0 : (f == 1 ? f1 : f2)) + (size_t)pl * CHAN_ * NFRAMES * RESO_;
  int lane = threadIdx.x & 63;
  int w = threadIdx.x >> 6;
  #pragma unroll
  for (int c = 0; c < 16; c++) {
    int cc = w * 16 + c;
    tile[cc][lane] = src[(size_t)cc * (NFRAMES * RESO_) + (size_t)t * RESO_ + xblk * 64 + lane];
  }
  __syncthreads();
  float* dst = T + ((size_t)(f * 3 + pl) * NFRAMES + t) * TROW + (size_t)(xblk * 64) * CHAN_;
  #pragma unroll
  for (int i = 0; i < 16; i++) {
    int xx = w * 16 + i;
    dst[(size_t)xx * CHAN_ + lane] = tile[lane][xx];
  }
}

__global__ __launch_bounds__(256) void scan_k(const int* __restrict__ bins,
                                              int* __restrict__ cursors) {
  __shared__ int part[256];
  const int tid = threadIdx.x;
  const int CHUNK = NBIN / 256;          // 25
  int loc[CHUNK];
  int s = 0;
  #pragma unroll
  for (int i = 0; i < CHUNK; i++) { loc[i] = s; s += bins[tid * CHUNK + i]; }
  part[tid] = s;
  __syncthreads();
  if (tid == 0) {
    int r = 0;
    for (int j = 0; j < 256; j++) { int v = part[j]; part[j] = r; r += v; }
  }
  __syncthreads();
  #pragma unroll
  for (int i = 0; i < CHUNK; i++) cursors[tid * CHUNK + i] = part[tid] + loc[i];
}

__global__ __launch_bounds__(256) void scatter_k(const float* __restrict__ xin,
                                                 int* __restrict__ cursors,
                                                 int* __restrict__ perm) {
  int p = blockIdx.x * 256 + threadIdx.x;
  if (p < P_N) {
    int pos = atomicAdd(&cursors[point_key(xin, p)], 1);
    perm[pos] = p;
  }
}

__device__ __forceinline__ float hw_sin_rev(float rev) {
  float r = rev - floorf(rev);
  float s;
  asm("v_sin_f32 %0, %1" : "=v"(s) : "v"(r));
  return s;
}

// 2 points per iteration: lanes 0-31 -> point 2k, lanes 32-63 -> point 2k+1.
// Lane holds channels (2l,2l+1) as float2. Waves own contiguous 32-point runs
// of the t-sorted order; XCD-swizzled block id keeps t-bins XCD-local.
// All 18 gathers batched before consumption; next x4 prefetched across iter.
__global__ __launch_bounds__(256) void sample_sorted_k(const float* __restrict__ xin,
                                                       const float* __restrict__ T,
                                                       const int* __restrict__ perm,
                                                       float* __restrict__ out) {
  const int lane = threadIdx.x & 63;
  const int half = lane >> 5;
  const int l = lane & 31;
  const int b = blockIdx.x;
  const int swz = (b & 7) * (4096 / 8) + (b >> 3);   // XCD-contiguous
  const int wave = swz * 4 + (threadIdx.x >> 6);
  const int base0 = wave * 32;                        // 16384 waves * 32 = P_N

  const int j = (lane >= 3) ? (lane - 3) : 0;
  const int fq = j / 6;
  const int rr = j - fq * 6;
  const int isc = rr / 3;
  const int dd = rr - isc * 3;
  const float scale = (float)(1 << fq);
  const float cosoff = isc ? 0.25f : 0.0f;
  const float inv2pi = 0.15915493667125702f;

  const float4* __restrict__ x4 = (const float4*)xin;

  // whole 32-point run's perm entries in one coalesced load
  const int permv = perm[base0 + (lane & 31)];

  int p_cur = __shfl(permv, half, 64);
  float4 c = x4[p_cur];

  #pragma unroll 4
  for (int k = 0; k < 16; k++) {
    int p_nxt = 0; float4 c_nxt = c;
    if (k < 15) {                          // prefetch next pair
      p_nxt = __shfl(permv, 2 * (k + 1) + half, 64);
      c_nxt = x4[p_nxt];
    }

    // t-axis: reference op order; dominant row (eps-row dropped)
    float tn = c.w / 99.0f;
    float gy = 2.0f * tn - 1.0f;
    float iy = ((gy + 1.0f) * 0.5f) * 99.0f;
    float y0f = floorf(iy);
    float wy1 = iy - y0f;
    int row; float wy;
    if (wy1 > 0.5f) { row = (int)y0f + 1; wy = wy1; }
    else            { row = (int)y0f;     wy = 1.0f - wy1; }
    row = min(max(row, 0), NFRAMES - 1);
    const int rowoff = row * TROW;

    // ---- batch all 18 gathers ----
    float wx1v[9];
    float2 v0[9], v1[9];
    float coords[3] = {c.x, c.y, c.z};
    #pragma unroll
    for (int s = 0; s < 9; s++) {
      int pl = s % 3;
      float gx = 2.0f * coords[pl] - 1.0f;
      float ix = ((gx + 1.0f) * 0.5f) * 255.0f;
      float x0f = floorf(ix);
      wx1v[s] = ix - x0f;
      int x0 = (int)x0f;                   // coords uniform [0,1) -> in-bounds
      const float2* rp = (const float2*)(T + (size_t)s * TPLANE
                                           + (size_t)(rowoff + x0 * CHAN_));
      v0[s] = rp[l];
      v1[s] = rp[l + 32];
    }

    // ---- consume ----
    float wy3 = wy * wy * wy;
    float dsum[3];
    #pragma unroll
    for (int f = 0; f < 3; f++) {
      float prx, pry;
      #pragma unroll
      for (int pl = 0; pl < 3; pl++) {
        int s = f * 3 + pl;
        float wx1 = wx1v[s], wx0 = 1.0f - wx1;
        float sx = v0[s].x * wx0 + v1[s].x * wx1;
        float sy = v0[s].y * wx0 + v1[s].y * wx1;
        if (pl == 0) { prx = sx; pry = sy; }
        else         { prx *= sx; pry *= sy; }
      }
      float r = (prx + pry) * wy3;
      #pragma unroll
      for (int m = 16; m > 0; m >>= 1) r += __shfl_xor(r, m, 64);
      dsum[f] = r;
    }

    float px = c.x + dsum[0];
    float py = c.y + dsum[1];
    float pz = c.z + dsum[2];

    #pragma unroll
    for (int q = 0; q < 2; q++) {
      float qx = __shfl(px, q * 32, 64);
      float qy = __shfl(py, q * 32, 64);
      float qz = __shfl(pz, q * 32, 64);
      int pq = __shfl(p_cur, q * 32, 64);
      float pd = (dd == 0) ? qx : (dd == 1) ? qy : qz;
      float ang = pd * scale;
      float val = hw_sin_rev(ang * inv2pi + cosoff);
      if (lane == 0) val = qx;
      else if (lane == 1) val = qy;
      else if (lane == 2) val = qz;
      if (lane < 63)
        __builtin_nontemporal_store(val, &out[(size_t)pq * 63 + lane]);
    }

    p_cur = p_nxt; c = c_nxt;
  }
}

// unsorted variant (ws fits T only)
__global__ __launch_bounds__(256) void sample2_k(const float* __restrict__ xin,
                                                 const float* __restrict__ T,
                                                 float* __restrict__ out) {
  const int lane = threadIdx.x & 63;
  const int half = lane >> 5;
  const int l = lane & 31;
  const int wave = blockIdx.x * 4 + (threadIdx.x >> 6);
  const int nW = gridDim.x * 4;
  const int j = (lane >= 3) ? (lane - 3) : 0;
  const int fq = j / 6;
  const int rr = j - fq * 6;
  const int isc = rr / 3;
  const int dd = rr - isc * 3;
  const float scale = (float)(1 << fq);
  const float cosoff = isc ? 0.25f : 0.0f;
  const float inv2pi = 0.15915493667125702f;
  const float4* __restrict__ x4 = (const float4*)xin;

  for (int base = wave * 2; base < P_N; base += nW * 2) {
    const int p = base + half;
    float4 c = x4[p];
    float tn = c.w / 99.0f;
    float gy = 2.0f * tn - 1.0f;
    float iy = ((gy + 1.0f) * 0.5f) * 99.0f;
    float y0f = floorf(iy);
    float wy1 = iy - y0f;
    int row; float wy;
    if (wy1 > 0.5f) { row = (int)y0f + 1; wy = wy1; }
    else            { row = (int)y0f;     wy = 1.0f - wy1; }
    row = min(max(row, 0), NFRAMES - 1);
    const int rowoff = row * TROW;
    float dsum[3];
    float coords[3] = {c.x, c.y, c.z};
    #pragma unroll
    for (int f = 0; f < 3; f++) {
      float prx, pry;
      #pragma unroll
      for (int pl = 0; pl < 3; pl++) {
        float gx = 2.0f * coords[pl] - 1.0f;
        float ix = ((gx + 1.0f) * 0.5f) * 255.0f;
        float x0f = floorf(ix);
        float wx1 = ix - x0f;
        float wx0 = 1.0f - wx1;
        int x0 = (int)x0f;
        const float2* rp = (const float2*)(T + (size_t)(f * 3 + pl) * TPLANE
                                             + (size_t)(rowoff + x0 * CHAN_));
        float2 v0 = rp[l];
        float2 v1 = rp[l + 32];
        float sx = (v0.x * wx0 + v1.x * wx1) * wy;
        float sy = (v0.y * wx0 + v1.y * wx1) * wy;
        if (pl == 0) { prx = sx; pry = sy; }
        else         { prx *= sx; pry *= sy; }
      }
      float r = prx + pry;
      #pragma unroll
      for (int m = 16; m > 0; m >>= 1) r += __shfl_xor(r, m, 64);
      dsum[f] = r;
    }
    float px = c.x + dsum[0];
    float py = c.y + dsum[1];
    float pz = c.z + dsum[2];
    #pragma unroll
    for (int q = 0; q < 2; q++) {
      float qx = __shfl(px, q * 32, 64);
      float qy = __shfl(py, q * 32, 64);
      float qz = __shfl(pz, q * 32, 64);
      float pd = (dd == 0) ? qx : (dd == 1) ? qy : qz;
      float ang = pd * scale;
      float val = hw_sin_rev(ang * inv2pi + cosoff);
      if (lane == 0) val = qx;
      else if (lane == 1) val = qy;
      else if (lane == 2) val = qz;
      if (lane < 63) out[(size_t)(base + q) * 63 + lane] = val;
    }
  }
}

// ---- fallback (no usable ws): direct-layout sampler ----
__global__ __launch_bounds__(256) void sample_fb_k(const float* __restrict__ xin,
                                                   const float* __restrict__ f0,
                                                   const float* __restrict__ f1,
                                                   const float* __restrict__ f2,
                                                   float* __restrict__ out) {
  const int lane = threadIdx.x & 63;
  int wave = blockIdx.x * 4 + (threadIdx.x >> 6);
  const int nW = gridDim.x * 4;
  for (int p = wave; p < P_N; p += nW) {
    float cx = xin[(size_t)p * 4 + 0];
    float cy = xin[(size_t)p * 4 + 1];
    float cz = xin[(size_t)p * 4 + 2];
    float ct = xin[(size_t)p * 4 + 3];
    float tn = ct / 99.0f;
    float gy = 2.0f * tn - 1.0f;
    float iy = ((gy + 1.0f) * 0.5f) * 99.0f;
    float y0f = floorf(iy);
    float wy1 = iy - y0f;
    float wy0 = 1.0f - wy1;
    int y0 = (int)y0f, y1 = y0 + 1;
    bool y0in = (unsigned)y0 < (unsigned)NFRAMES;
    bool y1in = (unsigned)y1 < (unsigned)NFRAMES;
    int y0c = min(max(y0, 0), NFRAMES - 1);
    int y1c = min(max(y1, 0), NFRAMES - 1);
    float d[3];
    #pragma unroll
    for (int f = 0; f < 3; f++) {
      float prodc;
      #pragma unroll
      for (int pl = 0; pl < 3; pl++) {
        float coord = (pl == 0) ? cx : (pl == 1) ? cy : cz;
        float gx = 2.0f * coord - 1.0f;
        float ix = ((gx + 1.0f) * 0.5f) * 255.0f;
        float x0f = floorf(ix);
        float wx1 = ix - x0f;
        float wx0 = 1.0f - wx1;
        int x0 = (int)x0f, x1 = x0 + 1;
        int x0c = min(max(x0, 0), RESO_ - 1);
        int x1c = min(max(x1, 0), RESO_ - 1);
        const float* ff = (f == 0) ? f0 : (f == 1) ? f1 : f2;
        const float* bse = ff + ((size_t)pl * CHAN_ + lane) * (NFRAMES * RESO_);
        float v00 = y0in ? bse[(size_t)y0c * RESO_ + x0c] : 0.0f;
        float v01 = y0in ? bse[(size_t)y0c * RESO_ + x1c] : 0.0f;
        float v10 = y1in ? bse[(size_t)y1c * RESO_ + x0c] : 0.0f;
        float v11 = y1in ? bse[(size_t)y1c * RESO_ + x1c] : 0.0f;
        float s = v00 * (wy0 * wx0) + v01 * (wy0 * wx1) + v10 * (wy1 * wx0) + v11 * (wy1 * wx1);
        prodc = (pl == 0) ? s : prodc * s;
      }
      float sum = prodc;
      #pragma unroll
      for (int o = 32; o > 0; o >>= 1) sum += __shfl_xor(sum, o, 64);
      d[f] = sum;
    }
    float p0 = cx + d[0], p1 = cy + d[1], p2 = cz + d[2];
    if (lane < 63) {
      float val;
      if (lane == 0) val = p0;
      else if (lane == 1) val = p1;
      else if (lane == 2) val = p2;
      else {
        int jj = lane - 3;
        int fq2 = jj / 6;
        int r2 = jj - fq2 * 6;
        int s2 = r2 / 3;
        int d2 = r2 - s2 * 3;
        float pd = (d2 == 0) ? p0 : (d2 == 1) ? p1 : p2;
        float ang = pd * (float)(1 << fq2);
        val = (s2 == 0) ? sinf(ang) : cosf(ang);
      }
      out[(size_t)p * 63 + lane] = val;
    }
  }
}

extern "C" void kernel_launch(void* const* d_in, const int* in_sizes, int n_in,
                              void* d_out, int out_size, void* d_ws, size_t ws_size,
                              hipStream_t stream) {
  const float* x  = (const float*)d_in[0];
  const float* f0 = (const float*)d_in[1];
  const float* f1 = (const float*)d_in[2];
  const float* f2 = (const float*)d_in[3];
  float* out = (float*)d_out;

  const size_t szT    = (size_t)9 * TPLANE * sizeof(float);     // ~59 MB
  const size_t szBins = (size_t)NBIN * sizeof(int);             // 25.6 KB
  const size_t szPerm = (size_t)P_N * sizeof(int);              // 2 MB
  const size_t needSorted = szT + 2 * szBins + szPerm;

  if (ws_size >= needSorted) {
    float* T      = (float*)d_ws;
    int* bins     = (int*)((char*)d_ws + szT);
    int* cursors  = (int*)((char*)d_ws + szT + szBins);
    int* perm     = (int*)((char*)d_ws + szT + 2 * szBins);
    hipMemsetAsync(bins, 0, szBins, stream);
    prep_k<<<dim3(NTRB + NHSB), dim3(256), 0, stream>>>(f0, f1, f2, T, x, bins);
    scan_k<<<dim3(1), dim3(256), 0, stream>>>(bins, cursors);
    scatter_k<<<dim3(NHSB), dim3(256), 0, stream>>>(x, cursors, perm);
    sample_sorted_k<<<dim3(4096), dim3(256), 0, stream>>>(x, T, perm, out);
  } else if (ws_size >= szT) {
    float* T = (float*)d_ws;
    prep_k<<<dim3(NTRB), dim3(256), 0, stream>>>(f0, f1, f2, T, x, nullptr);
    sample2_k<<<dim3(4096), dim3(256), 0, stream>>>(x, T, out);
  } else {
    sample_fb_k<<<dim3(8192), dim3(256), 0, stream>>>(x, f0, f1, f2, out);
  }
}

// Round 5
// 257.830 us; speedup vs baseline: 2.5506x; 1.0011x over previous
//
#include <hip/hip_runtime.h>
#include <math.h>

#define P_N 524288
#define NFRAMES 100
#define RESO_ 256
#define CHAN_ 64
#define NFREQ 10

// Transposed layout: T[(f*3+pl)][t][x][c] ; c contiguous
#define TROW   (RESO_ * CHAN_)          // 16384 floats per t-row
#define TPLANE (NFRAMES * TROW)         // 1,638,400 floats per plane

#define NSUB 64
#define NBIN (NFRAMES * NSUB)           // 6400 buckets: key = t*64 + (p>>13)
#define NTRB (3 * 3 * NFRAMES * 4)      // 3600 transpose blocks
#define NHSB (P_N / 256)                // 2048 hist/scatter blocks

__device__ __forceinline__ int point_key(const float* xin, int p) {
  float ct = xin[(size_t)p * 4 + 3];
  int t = (int)ct;
  t = min(max(t, 0), NFRAMES - 1);
  return t * NSUB + (p >> 13);
}

// fused: blocks [0,NTRB) transpose features; blocks [NTRB, NTRB+NHSB) histogram
__global__ __launch_bounds__(256) void prep_k(const float* __restrict__ f0,
                                              const float* __restrict__ f1,
                                              const float* __restrict__ f2,
                                              float* __restrict__ T,
                                              const float* __restrict__ xin,
                                              int* __restrict__ bins) {
  if (blockIdx.x >= NTRB) {
    int p = (blockIdx.x - NTRB) * 256 + threadIdx.x;
    if (p < P_N) atomicAdd(&bins[point_key(xin, p)], 1);
    return;
  }
  __shared__ float tile[64][65];
  int b = blockIdx.x;
  int xblk = b & 3; b >>= 2;                 // 4 x-tiles of 64
  int t = b % NFRAMES; b /= NFRAMES;
  int pl = b % 3; int f = b / 3;
  const float* src = (f == 0 ? f0 : (f == 1 ? f1 : f2)) + (size_t)pl * CHAN_ * NFRAMES * RESO_;
  int lane = threadIdx.x & 63;
  int w = threadIdx.x >> 6;
  #pragma unroll
  for (int c = 0; c < 16; c++) {
    int cc = w * 16 + c;
    tile[cc][lane] = src[(size_t)cc * (NFRAMES * RESO_) + (size_t)t * RESO_ + xblk * 64 + lane];
  }
  __syncthreads();
  float* dst = T + ((size_t)(f * 3 + pl) * NFRAMES + t) * TROW + (size_t)(xblk * 64) * CHAN_;
  #pragma unroll
  for (int i = 0; i < 16; i++) {
    int xx = w * 16 + i;
    dst[(size_t)xx * CHAN_ + lane] = tile[lane][xx];
  }
}

__global__ __launch_bounds__(256) void scan_k(const int* __restrict__ bins,
                                              int* __restrict__ cursors) {
  __shared__ int part[256];
  const int tid = threadIdx.x;
  const int CHUNK = NBIN / 256;          // 25
  int loc[CHUNK];
  int s = 0;
  #pragma unroll
  for (int i = 0; i < CHUNK; i++) { loc[i] = s; s += bins[tid * CHUNK + i]; }
  part[tid] = s;
  __syncthreads();
  if (tid == 0) {
    int r = 0;
    for (int j = 0; j < 256; j++) { int v = part[j]; part[j] = r; r += v; }
  }
  __syncthreads();
  #pragma unroll
  for (int i = 0; i < CHUNK; i++) cursors[tid * CHUNK + i] = part[tid] + loc[i];
}

__global__ __launch_bounds__(256) void scatter_k(const float* __restrict__ xin,
                                                 int* __restrict__ cursors,
                                                 int* __restrict__ perm) {
  int p = blockIdx.x * 256 + threadIdx.x;
  if (p < P_N) {
    int pos = atomicAdd(&cursors[point_key(xin, p)], 1);
    perm[pos] = p;
  }
}

__device__ __forceinline__ float hw_sin_rev(float rev) {
  float r = rev - floorf(rev);
  float s;
  asm("v_sin_f32 %0, %1" : "=v"(s) : "v"(r));
  return s;
}

// STAGE: compute weights + issue all 18 gathers for one pair into buffer set
#define STAGE(W, V0, V1, c, wy3out)                                          \
  {                                                                          \
    float tn = (c).w / 99.0f;                                                \
    float gy = 2.0f * tn - 1.0f;                                             \
    float iy = ((gy + 1.0f) * 0.5f) * 99.0f;                                 \
    float y0f = floorf(iy);                                                  \
    float wy1_ = iy - y0f;                                                   \
    int row; float wy_;                                                      \
    if (wy1_ > 0.5f) { row = (int)y0f + 1; wy_ = wy1_; }                     \
    else             { row = (int)y0f;     wy_ = 1.0f - wy1_; }              \
    row = min(max(row, 0), NFRAMES - 1);                                     \
    const int rowoff_ = row * TROW;                                          \
    (wy3out) = wy_ * wy_ * wy_;                                              \
    float crd_[3] = {(c).x, (c).y, (c).z};                                   \
    _Pragma("unroll")                                                        \
    for (int s = 0; s < 9; s++) {                                            \
      float gx = 2.0f * crd_[s % 3] - 1.0f;                                  \
      float ix = ((gx + 1.0f) * 0.5f) * 255.0f;                              \
      float x0f = floorf(ix);                                                \
      (W)[s] = ix - x0f;                                                     \
      int x0 = (int)x0f;                                                     \
      const float2* rp = (const float2*)(T + (size_t)s * TPLANE              \
                                           + (size_t)(rowoff_ + x0 * CHAN_));\
      (V0)[s] = rp[l];                                                       \
      (V1)[s] = rp[l + 32];                                                  \
    }                                                                        \
  }

// CONSUME: lerp+product+reduce+PE+store for one pair
#define CONSUME(W, V0, V1, wy3, c, p)                                        \
  {                                                                          \
    float dsum_[3];                                                          \
    _Pragma("unroll")                                                        \
    for (int f = 0; f < 3; f++) {                                            \
      float prx, pry;                                                        \
      _Pragma("unroll")                                                      \
      for (int pl = 0; pl < 3; pl++) {                                       \
        int s = f * 3 + pl;                                                  \
        float w1 = (W)[s], w0 = 1.0f - w1;                                   \
        float sx = (V0)[s].x * w0 + (V1)[s].x * w1;                          \
        float sy = (V0)[s].y * w0 + (V1)[s].y * w1;                          \
        if (pl == 0) { prx = sx; pry = sy; }                                 \
        else         { prx *= sx; pry *= sy; }                               \
      }                                                                      \
      float r = (prx + pry) * (wy3);                                         \
      _Pragma("unroll")                                                      \
      for (int m = 16; m > 0; m >>= 1) r += __shfl_xor(r, m, 64);            \
      dsum_[f] = r;                                                          \
    }                                                                        \
    float px = (c).x + dsum_[0];                                             \
    float py = (c).y + dsum_[1];                                             \
    float pz = (c).z + dsum_[2];                                             \
    _Pragma("unroll")                                                        \
    for (int q = 0; q < 2; q++) {                                            \
      float qx = __shfl(px, q * 32, 64);                                     \
      float qy = __shfl(py, q * 32, 64);                                     \
      float qz = __shfl(pz, q * 32, 64);                                     \
      int pq = __shfl((p), q * 32, 64);                                      \
      float pd = (dd == 0) ? qx : (dd == 1) ? qy : qz;                       \
      float val = hw_sin_rev(pd * scale * inv2pi + cosoff);                  \
      if (lane == 0) val = qx;                                               \
      else if (lane == 1) val = qy;                                          \
      else if (lane == 2) val = qz;                                          \
      if (lane < 63)                                                         \
        __builtin_nontemporal_store(val, &out[(size_t)pq * 63 + lane]);      \
    }                                                                        \
  }

// 2 points/iteration (half-waves); depth-2 software pipeline over pairs:
// set X staged (18 gathers in flight) while set Y is consumed; x4 of the
// pair-after-next prefetched. Waves own contiguous 32-point runs of the
// t-sorted order; XCD-swizzled block id keeps t-bins XCD-local.
__global__ __launch_bounds__(256) void sample_sorted_k(const float* __restrict__ xin,
                                                       const float* __restrict__ T,
                                                       const int* __restrict__ perm,
                                                       float* __restrict__ out) {
  const int lane = threadIdx.x & 63;
  const int half = lane >> 5;
  const int l = lane & 31;
  const int b = blockIdx.x;
  const int swz = (b & 7) * (4096 / 8) + (b >> 3);   // XCD-contiguous
  const int wave = swz * 4 + (threadIdx.x >> 6);
  const int base0 = wave * 32;                        // 16384 waves * 32 = P_N

  const int j = (lane >= 3) ? (lane - 3) : 0;
  const int fq = j / 6;
  const int rr = j - fq * 6;
  const int isc = rr / 3;
  const int dd = rr - isc * 3;
  const float scale = (float)(1 << fq);
  const float cosoff = isc ? 0.25f : 0.0f;
  const float inv2pi = 0.15915493667125702f;

  const float4* __restrict__ x4 = (const float4*)xin;

  // whole 32-point run's perm entries in one coalesced load
  const int permv = perm[base0 + (lane & 31)];

  float2 vA0[9], vA1[9], vB0[9], vB1[9];
  float wA[9], wB[9];
  float wy3A, wy3B;

  // prologue: stage pair 0, load x of pair 1
  int pA = __shfl(permv, half, 64);
  float4 cA = x4[pA];
  STAGE(wA, vA0, vA1, cA, wy3A);
  int pB = __shfl(permv, 2 + half, 64);
  float4 cB = x4[pB];

  // steady state: pairs 0..13 consumed here (guards all true, loop dynamic)
  #pragma unroll 1
  for (int kk = 0; kk < 7; kk++) {
    const int k = kk * 2;
    // even body: A in flight (pair k), cB = x of pair k+1
    STAGE(wB, vB0, vB1, cB, wy3B);                     // pair k+1 in flight
    {
      float4 cF = cA; int pF = pA;
      pA = __shfl(permv, 2 * (k + 2) + half, 64);      // prefetch pair k+2
      cA = x4[pA];
      CONSUME(wA, vA0, vA1, wy3A, cF, pF);             // consume pair k
    }
    // odd body: B in flight (pair k+1), cA = x of pair k+2
    STAGE(wA, vA0, vA1, cA, wy3A);                     // pair k+2 in flight
    {
      float4 cF = cB; int pF = pB;
      pB = __shfl(permv, 2 * (k + 3) + half, 64);      // prefetch pair k+3
      cB = x4[pB];
      CONSUME(wB, vB0, vB1, wy3B, cF, pF);             // consume pair k+1
    }
  }
  // epilogue: A in flight (pair 14), cB = x of pair 15
  STAGE(wB, vB0, vB1, cB, wy3B);                       // pair 15 in flight
  CONSUME(wA, vA0, vA1, wy3A, cA, pA);                 // pair 14
  CONSUME(wB, vB0, vB1, wy3B, cB, pB);                 // pair 15
}

// unsorted variant (ws fits T only)
__global__ __launch_bounds__(256) void sample2_k(const float* __restrict__ xin,
                                                 const float* __restrict__ T,
                                                 float* __restrict__ out) {
  const int lane = threadIdx.x & 63;
  const int half = lane >> 5;
  const int l = lane & 31;
  const int wave = blockIdx.x * 4 + (threadIdx.x >> 6);
  const int nW = gridDim.x * 4;
  const int j = (lane >= 3) ? (lane - 3) : 0;
  const int fq = j / 6;
  const int rr = j - fq * 6;
  const int isc = rr / 3;
  const int dd = rr - isc * 3;
  const float scale = (float)(1 << fq);
  const float cosoff = isc ? 0.25f : 0.0f;
  const float inv2pi = 0.15915493667125702f;
  const float4* __restrict__ x4 = (const float4*)xin;

  for (int base = wave * 2; base < P_N; base += nW * 2) {
    const int p = base + half;
    float4 c = x4[p];
    float wy3;
    float2 v0[9], v1[9];
    float wv[9];
    STAGE(wv, v0, v1, c, wy3);
    CONSUME(wv, v0, v1, wy3, c, p);
  }
}

// ---- fallback (no usable ws): direct-layout sampler ----
__global__ __launch_bounds__(256) void sample_fb_k(const float* __restrict__ xin,
                                                   const float* __restrict__ f0,
                                                   const float* __restrict__ f1,
                                                   const float* __restrict__ f2,
                                                   float* __restrict__ out) {
  const int lane = threadIdx.x & 63;
  int wave = blockIdx.x * 4 + (threadIdx.x >> 6);
  const int nW = gridDim.x * 4;
  for (int p = wave; p < P_N; p += nW) {
    float cx = xin[(size_t)p * 4 + 0];
    float cy = xin[(size_t)p * 4 + 1];
    float cz = xin[(size_t)p * 4 + 2];
    float ct = xin[(size_t)p * 4 + 3];
    float tn = ct / 99.0f;
    float gy = 2.0f * tn - 1.0f;
    float iy = ((gy + 1.0f) * 0.5f) * 99.0f;
    float y0f = floorf(iy);
    float wy1 = iy - y0f;
    float wy0 = 1.0f - wy1;
    int y0 = (int)y0f, y1 = y0 + 1;
    bool y0in = (unsigned)y0 < (unsigned)NFRAMES;
    bool y1in = (unsigned)y1 < (unsigned)NFRAMES;
    int y0c = min(max(y0, 0), NFRAMES - 1);
    int y1c = min(max(y1, 0), NFRAMES - 1);
    float d[3];
    #pragma unroll
    for (int f = 0; f < 3; f++) {
      float prodc;
      #pragma unroll
      for (int pl = 0; pl < 3; pl++) {
        float coord = (pl == 0) ? cx : (pl == 1) ? cy : cz;
        float gx = 2.0f * coord - 1.0f;
        float ix = ((gx + 1.0f) * 0.5f) * 255.0f;
        float x0f = floorf(ix);
        float wx1 = ix - x0f;
        float wx0 = 1.0f - wx1;
        int x0 = (int)x0f, x1 = x0 + 1;
        int x0c = min(max(x0, 0), RESO_ - 1);
        int x1c = min(max(x1, 0), RESO_ - 1);
        const float* ff = (f == 0) ? f0 : (f == 1) ? f1 : f2;
        const float* bse = ff + ((size_t)pl * CHAN_ + lane) * (NFRAMES * RESO_);
        float v00 = y0in ? bse[(size_t)y0c * RESO_ + x0c] : 0.0f;
        float v01 = y0in ? bse[(size_t)y0c * RESO_ + x1c] : 0.0f;
        float v10 = y1in ? bse[(size_t)y1c * RESO_ + x0c] : 0.0f;
        float v11 = y1in ? bse[(size_t)y1c * RESO_ + x1c] : 0.0f;
        float s = v00 * (wy0 * wx0) + v01 * (wy0 * wx1) + v10 * (wy1 * wx0) + v11 * (wy1 * wx1);
        prodc = (pl == 0) ? s : prodc * s;
      }
      float sum = prodc;
      #pragma unroll
      for (int o = 32; o > 0; o >>= 1) sum += __shfl_xor(sum, o, 64);
      d[f] = sum;
    }
    float p0 = cx + d[0], p1 = cy + d[1], p2 = cz + d[2];
    if (lane < 63) {
      float val;
      if (lane == 0) val = p0;
      else if (lane == 1) val = p1;
      else if (lane == 2) val = p2;
      else {
        int jj = lane - 3;
        int fq2 = jj / 6;
        int r2 = jj - fq2 * 6;
        int s2 = r2 / 3;
        int d2 = r2 - s2 * 3;
        float pd = (d2 == 0) ? p0 : (d2 == 1) ? p1 : p2;
        float ang = pd * (float)(1 << fq2);
        val = (s2 == 0) ? sinf(ang) : cosf(ang);
      }
      out[(size_t)p * 63 + lane] = val;
    }
  }
}

extern "C" void kernel_launch(void* const* d_in, const int* in_sizes, int n_in,
                              void* d_out, int out_size, void* d_ws, size_t ws_size,
                              hipStream_t stream) {
  const float* x  = (const float*)d_in[0];
  const float* f0 = (const float*)d_in[1];
  const float* f1 = (const float*)d_in[2];
  const float* f2 = (const float*)d_in[3];
  float* out = (float*)d_out;

  const size_t szT    = (size_t)9 * TPLANE * sizeof(float);     // ~59 MB
  const size_t szBins = (size_t)NBIN * sizeof(int);             // 25.6 KB
  const size_t szPerm = (size_t)P_N * sizeof(int);              // 2 MB
  const size_t needSorted = szT + 2 * szBins + szPerm;

  if (ws_size >= needSorted) {
    float* T      = (float*)d_ws;
    int* bins     = (int*)((char*)d_ws + szT);
    int* cursors  = (int*)((char*)d_ws + szT + szBins);
    int* perm     = (int*)((char*)d_ws + szT + 2 * szBins);
    hipMemsetAsync(bins, 0, szBins, stream);
    prep_k<<<dim3(NTRB + NHSB), dim3(256), 0, stream>>>(f0, f1, f2, T, x, bins);
    scan_k<<<dim3(1), dim3(256), 0, stream>>>(bins, cursors);
    scatter_k<<<dim3(NHSB), dim3(256), 0, stream>>>(x, cursors, perm);
    sample_sorted_k<<<dim3(4096), dim3(256), 0, stream>>>(x, T, perm, out);
  } else if (ws_size >= szT) {
    float* T = (float*)d_ws;
    prep_k<<<dim3(NTRB), dim3(256), 0, stream>>>(f0, f1, f2, T, x, nullptr);
    sample2_k<<<dim3(4096), dim3(256), 0, stream>>>(x, T, out);
  } else {
    sample_fb_k<<<dim3(8192), dim3(256), 0, stream>>>(x, f0, f1, f2, out);
  }
}

// Round 6
// 214.584 us; speedup vs baseline: 3.0646x; 1.2015x over previous
//
#include <hip/hip_runtime.h>
#include <math.h>

#define P_N 524288
#define NFRAMES 100
#define RESO_ 256
#define CHAN_ 64
#define NFREQ 10

// Transposed layout: T[(f*3+pl)][t][x][c] ; c contiguous
#define TROW   (RESO_ * CHAN_)          // 16384 floats per t-row
#define TPLANE (NFRAMES * TROW)         // 1,638,400 floats per plane

#define NSUB 64
#define NBIN (NFRAMES * NSUB)           // 6400 buckets: key = t*64 + (p>>13)
#define NTRB (3 * 3 * NFRAMES * 4)      // 3600 transpose blocks
#define NHSB (P_N / 256)                // 2048 hist/scatter blocks

__device__ __forceinline__ int point_key(const float* xin, int p) {
  float ct = xin[(size_t)p * 4 + 3];
  int t = (int)ct;
  t = min(max(t, 0), NFRAMES - 1);
  return t * NSUB + (p >> 13);
}

// fused: blocks [0,NTRB) transpose features; blocks [NTRB, NTRB+NHSB) histogram
__global__ __launch_bounds__(256) void prep_k(const float* __restrict__ f0,
                                              const float* __restrict__ f1,
                                              const float* __restrict__ f2,
                                              float* __restrict__ T,
                                              const float* __restrict__ xin,
                                              int* __restrict__ bins) {
  if (blockIdx.x >= NTRB) {
    int p = (blockIdx.x - NTRB) * 256 + threadIdx.x;
    if (p < P_N) atomicAdd(&bins[point_key(xin, p)], 1);
    return;
  }
  __shared__ float tile[64][65];
  int b = blockIdx.x;
  int xblk = b & 3; b >>= 2;                 // 4 x-tiles of 64
  int t = b % NFRAMES; b /= NFRAMES;
  int pl = b % 3; int f = b / 3;
  const float* src = (f == 0 ? f0 : (f == 1 ? f1 : f2)) + (size_t)pl * CHAN_ * NFRAMES * RESO_;
  int lane = threadIdx.x & 63;
  int w = threadIdx.x >> 6;
  #pragma unroll
  for (int c = 0; c < 16; c++) {
    int cc = w * 16 + c;
    tile[cc][lane] = src[(size_t)cc * (NFRAMES * RESO_) + (size_t)t * RESO_ + xblk * 64 + lane];
  }
  __syncthreads();
  float* dst = T + ((size_t)(f * 3 + pl) * NFRAMES + t) * TROW + (size_t)(xblk * 64) * CHAN_;
  #pragma unroll
  for (int i = 0; i < 16; i++) {
    int xx = w * 16 + i;
    dst[(size_t)xx * CHAN_ + lane] = tile[lane][xx];
  }
}

__global__ __launch_bounds__(256) void scan_k(const int* __restrict__ bins,
                                              int* __restrict__ cursors) {
  __shared__ int part[256];
  const int tid = threadIdx.x;
  const int CHUNK = NBIN / 256;          // 25
  int loc[CHUNK];
  int s = 0;
  #pragma unroll
  for (int i = 0; i < CHUNK; i++) { loc[i] = s; s += bins[tid * CHUNK + i]; }
  part[tid] = s;
  __syncthreads();
  if (tid == 0) {
    int r = 0;
    for (int j = 0; j < 256; j++) { int v = part[j]; part[j] = r; r += v; }
  }
  __syncthreads();
  #pragma unroll
  for (int i = 0; i < CHUNK; i++) cursors[tid * CHUNK + i] = part[tid] + loc[i];
}

__global__ __launch_bounds__(256) void scatter_k(const float* __restrict__ xin,
                                                 int* __restrict__ cursors,
                                                 int* __restrict__ perm) {
  int p = blockIdx.x * 256 + threadIdx.x;
  if (p < P_N) {
    int pos = atomicAdd(&cursors[point_key(xin, p)], 1);
    perm[pos] = p;
  }
}

__device__ __forceinline__ float hw_sin_rev(float rev) {
  float r = rev - floorf(rev);
  float s;
  asm("v_sin_f32 %0, %1" : "=v"(s) : "v"(r));
  return s;
}

// 4 points per wave iteration: lane-group g = lane>>4 owns point k*4+g.
// Each 16-lane group loads full 64-channel rows as float4 (row = 256 B =
// 16 lanes x 16 B). 18 row-loads + 1 coord prefetch batched, then
// sched_barrier(0) pins the batch before consumption (R5 lesson: without
// the fence the compiler re-sinks loads to uses, killing MLP).
__global__ __launch_bounds__(256) void sample4_k(const float* __restrict__ xin,
                                                 const float* __restrict__ T,
                                                 const int* __restrict__ perm,
                                                 float* __restrict__ out) {
  const int lane = threadIdx.x & 63;
  const int g = lane >> 4;          // group 0..3
  const int sl = lane & 15;         // sub-lane in group
  const int b = blockIdx.x;
  const int swz = (b & 7) * (2048 / 8) + (b >> 3);   // XCD-contiguous, bijective (2048%8==0)
  const int wave = swz * 4 + (threadIdx.x >> 6);
  const int base0 = wave * 64;                        // 8192 waves * 64 = P_N

  // per-lane PE constants (output element id = lane, valid for lane<63)
  const int j = (lane >= 3) ? (lane - 3) : 0;
  const int fq = j / 6;
  const int rr = j - fq * 6;
  const int isc = rr / 3;
  const int dd = rr - isc * 3;
  const float scale = (float)(1 << fq);
  const float cosoff = isc ? 0.25f : 0.0f;
  const float inv2pi = 0.15915493667125702f;

  const float4* __restrict__ x4 = (const float4*)xin;

  // whole 64-point run's perm entries in one coalesced load
  const int permv = perm[base0 + lane];

  int p_cur = __shfl(permv, g, 64);
  float4 c = x4[p_cur];

  #pragma unroll 2
  for (int k = 0; k < 16; k++) {
    // ---- STAGE: weights + all 18 row-gathers + next coord prefetch ----
    float tn = c.w / 99.0f;
    float gy = 2.0f * tn - 1.0f;
    float iy = ((gy + 1.0f) * 0.5f) * 99.0f;
    float y0f = floorf(iy);
    float wy1 = iy - y0f;
    int row; float wy;
    if (wy1 > 0.5f) { row = (int)y0f + 1; wy = wy1; }
    else            { row = (int)y0f;     wy = 1.0f - wy1; }
    row = min(max(row, 0), NFRAMES - 1);
    const int rowoff = row * TROW;

    float wx1v[9];
    float4 v0[9], v1[9];
    float crd[3] = {c.x, c.y, c.z};
    #pragma unroll
    for (int s = 0; s < 9; s++) {
      float gx = 2.0f * crd[s % 3] - 1.0f;
      float ix = ((gx + 1.0f) * 0.5f) * 255.0f;
      float x0f = floorf(ix);
      wx1v[s] = ix - x0f;
      int x0 = (int)x0f;                   // coords uniform [0,1) -> 0..254
      const float4* rp = (const float4*)(T + (size_t)s * TPLANE
                                           + (size_t)(rowoff + x0 * CHAN_));
      v0[s] = rp[sl];                      // x0 row, channels 4sl..4sl+3
      v1[s] = rp[sl + 16];                 // x0+1 row
    }
    int p_nxt = 0; float4 c_nxt = c;
    if (k < 15) {
      p_nxt = __shfl(permv, (k + 1) * 4 + g, 64);
      c_nxt = x4[p_nxt];
    }
    __builtin_amdgcn_sched_barrier(0);     // pin the 19-load batch above

    // ---- CONSUME ----
    float wy3 = wy * wy * wy;
    float dsum[3];
    #pragma unroll
    for (int f = 0; f < 3; f++) {
      float prx, pry, prz, prw;
      #pragma unroll
      for (int pl = 0; pl < 3; pl++) {
        int s = f * 3 + pl;
        float w1 = wx1v[s];
        float sx = fmaf(w1, v1[s].x - v0[s].x, v0[s].x);
        float sy = fmaf(w1, v1[s].y - v0[s].y, v0[s].y);
        float sz = fmaf(w1, v1[s].z - v0[s].z, v0[s].z);
        float sw = fmaf(w1, v1[s].w - v0[s].w, v0[s].w);
        if (pl == 0) { prx = sx; pry = sy; prz = sz; prw = sw; }
        else         { prx *= sx; pry *= sy; prz *= sz; prw *= sw; }
      }
      float r = ((prx + pry) + (prz + prw)) * wy3;
      #pragma unroll
      for (int m = 8; m > 0; m >>= 1) r += __shfl_xor(r, m, 64);  // 16-group
      dsum[f] = r;
    }

    float px = c.x + dsum[0];
    float py = c.y + dsum[1];
    float pz = c.z + dsum[2];

    // ---- PE + store: 4 rounds, one point each ----
    #pragma unroll
    for (int q = 0; q < 4; q++) {
      float qx = __shfl(px, q * 16, 64);
      float qy = __shfl(py, q * 16, 64);
      float qz = __shfl(pz, q * 16, 64);
      int pq = __shfl(p_cur, q * 16, 64);
      float pd = (dd == 0) ? qx : (dd == 1) ? qy : qz;
      float val = hw_sin_rev(pd * scale * inv2pi + cosoff);
      if (lane == 0) val = qx;
      else if (lane == 1) val = qy;
      else if (lane == 2) val = qz;
      if (lane < 63)
        __builtin_nontemporal_store(val, &out[(size_t)pq * 63 + lane]);
    }

    p_cur = p_nxt; c = c_nxt;
  }
}

// ---- unsorted variant (ws fits T only): 2-pt/wave, float2 channel pairs ----
__global__ __launch_bounds__(256) void sample2_k(const float* __restrict__ xin,
                                                 const float* __restrict__ T,
                                                 float* __restrict__ out) {
  const int lane = threadIdx.x & 63;
  const int half = lane >> 5;
  const int l = lane & 31;
  const int wave = blockIdx.x * 4 + (threadIdx.x >> 6);
  const int nW = gridDim.x * 4;
  const int j = (lane >= 3) ? (lane - 3) : 0;
  const int fq = j / 6;
  const int rr = j - fq * 6;
  const int isc = rr / 3;
  const int dd = rr - isc * 3;
  const float scale = (float)(1 << fq);
  const float cosoff = isc ? 0.25f : 0.0f;
  const float inv2pi = 0.15915493667125702f;
  const float4* __restrict__ x4 = (const float4*)xin;

  for (int base = wave * 2; base < P_N; base += nW * 2) {
    const int p = base + half;
    float4 c = x4[p];
    float tn = c.w / 99.0f;
    float gy = 2.0f * tn - 1.0f;
    float iy = ((gy + 1.0f) * 0.5f) * 99.0f;
    float y0f = floorf(iy);
    float wy1 = iy - y0f;
    int row; float wy;
    if (wy1 > 0.5f) { row = (int)y0f + 1; wy = wy1; }
    else            { row = (int)y0f;     wy = 1.0f - wy1; }
    row = min(max(row, 0), NFRAMES - 1);
    const int rowoff = row * TROW;
    float dsum[3];
    float crd[3] = {c.x, c.y, c.z};
    #pragma unroll
    for (int f = 0; f < 3; f++) {
      float prx, pry;
      #pragma unroll
      for (int pl = 0; pl < 3; pl++) {
        float gx = 2.0f * crd[pl] - 1.0f;
        float ix = ((gx + 1.0f) * 0.5f) * 255.0f;
        float x0f = floorf(ix);
        float wx1 = ix - x0f;
        float wx0 = 1.0f - wx1;
        int x0 = (int)x0f;
        const float2* rp = (const float2*)(T + (size_t)(f * 3 + pl) * TPLANE
                                             + (size_t)(rowoff + x0 * CHAN_));
        float2 v0 = rp[l];
        float2 v1 = rp[l + 32];
        float sx = (v0.x * wx0 + v1.x * wx1) * wy;
        float sy = (v0.y * wx0 + v1.y * wx1) * wy;
        if (pl == 0) { prx = sx; pry = sy; }
        else         { prx *= sx; pry *= sy; }
      }
      float r = prx + pry;
      #pragma unroll
      for (int m = 16; m > 0; m >>= 1) r += __shfl_xor(r, m, 64);
      dsum[f] = r;
    }
    float px = c.x + dsum[0];
    float py = c.y + dsum[1];
    float pz = c.z + dsum[2];
    #pragma unroll
    for (int q = 0; q < 2; q++) {
      float qx = __shfl(px, q * 32, 64);
      float qy = __shfl(py, q * 32, 64);
      float qz = __shfl(pz, q * 32, 64);
      float pd = (dd == 0) ? qx : (dd == 1) ? qy : qz;
      float val = hw_sin_rev(pd * scale * inv2pi + cosoff);
      if (lane == 0) val = qx;
      else if (lane == 1) val = qy;
      else if (lane == 2) val = qz;
      if (lane < 63) out[(size_t)(base + q) * 63 + lane] = val;
    }
  }
}

// ---- fallback (no usable ws): direct-layout sampler ----
__global__ __launch_bounds__(256) void sample_fb_k(const float* __restrict__ xin,
                                                   const float* __restrict__ f0,
                                                   const float* __restrict__ f1,
                                                   const float* __restrict__ f2,
                                                   float* __restrict__ out) {
  const int lane = threadIdx.x & 63;
  int wave = blockIdx.x * 4 + (threadIdx.x >> 6);
  const int nW = gridDim.x * 4;
  for (int p = wave; p < P_N; p += nW) {
    float cx = xin[(size_t)p * 4 + 0];
    float cy = xin[(size_t)p * 4 + 1];
    float cz = xin[(size_t)p * 4 + 2];
    float ct = xin[(size_t)p * 4 + 3];
    float tn = ct / 99.0f;
    float gy = 2.0f * tn - 1.0f;
    float iy = ((gy + 1.0f) * 0.5f) * 99.0f;
    float y0f = floorf(iy);
    float wy1 = iy - y0f;
    float wy0 = 1.0f - wy1;
    int y0 = (int)y0f, y1 = y0 + 1;
    bool y0in = (unsigned)y0 < (unsigned)NFRAMES;
    bool y1in = (unsigned)y1 < (unsigned)NFRAMES;
    int y0c = min(max(y0, 0), NFRAMES - 1);
    int y1c = min(max(y1, 0), NFRAMES - 1);
    float d[3];
    #pragma unroll
    for (int f = 0; f < 3; f++) {
      float prodc;
      #pragma unroll
      for (int pl = 0; pl < 3; pl++) {
        float coord = (pl == 0) ? cx : (pl == 1) ? cy : cz;
        float gx = 2.0f * coord - 1.0f;
        float ix = ((gx + 1.0f) * 0.5f) * 255.0f;
        float x0f = floorf(ix);
        float wx1 = ix - x0f;
        float wx0 = 1.0f - wx1;
        int x0 = (int)x0f, x1 = x0 + 1;
        int x0c = min(max(x0, 0), RESO_ - 1);
        int x1c = min(max(x1, 0), RESO_ - 1);
        const float* ff = (f == 0) ? f0 : (f == 1) ? f1 : f2;
        const float* bse = ff + ((size_t)pl * CHAN_ + lane) * (NFRAMES * RESO_);
        float v00 = y0in ? bse[(size_t)y0c * RESO_ + x0c] : 0.0f;
        float v01 = y0in ? bse[(size_t)y0c * RESO_ + x1c] : 0.0f;
        float v10 = y1in ? bse[(size_t)y1c * RESO_ + x0c] : 0.0f;
        float v11 = y1in ? bse[(size_t)y1c * RESO_ + x1c] : 0.0f;
        float s = v00 * (wy0 * wx0) + v01 * (wy0 * wx1) + v10 * (wy1 * wx0) + v11 * (wy1 * wx1);
        prodc = (pl == 0) ? s : prodc * s;
      }
      float sum = prodc;
      #pragma unroll
      for (int o = 32; o > 0; o >>= 1) sum += __shfl_xor(sum, o, 64);
      d[f] = sum;
    }
    float p0 = cx + d[0], p1 = cy + d[1], p2 = cz + d[2];
    if (lane < 63) {
      float val;
      if (lane == 0) val = p0;
      else if (lane == 1) val = p1;
      else if (lane == 2) val = p2;
      else {
        int jj = lane - 3;
        int fq2 = jj / 6;
        int r2 = jj - fq2 * 6;
        int s2 = r2 / 3;
        int d2 = r2 - s2 * 3;
        float pd = (d2 == 0) ? p0 : (d2 == 1) ? p1 : p2;
        float ang = pd * (float)(1 << fq2);
        val = (s2 == 0) ? sinf(ang) : cosf(ang);
      }
      out[(size_t)p * 63 + lane] = val;
    }
  }
}

extern "C" void kernel_launch(void* const* d_in, const int* in_sizes, int n_in,
                              void* d_out, int out_size, void* d_ws, size_t ws_size,
                              hipStream_t stream) {
  const float* x  = (const float*)d_in[0];
  const float* f0 = (const float*)d_in[1];
  const float* f1 = (const float*)d_in[2];
  const float* f2 = (const float*)d_in[3];
  float* out = (float*)d_out;

  const size_t szT    = (size_t)9 * TPLANE * sizeof(float);     // ~59 MB
  const size_t szBins = (size_t)NBIN * sizeof(int);             // 25.6 KB
  const size_t szPerm = (size_t)P_N * sizeof(int);              // 2 MB
  const size_t needSorted = szT + 2 * szBins + szPerm;

  if (ws_size >= needSorted) {
    float* T      = (float*)d_ws;
    int* bins     = (int*)((char*)d_ws + szT);
    int* cursors  = (int*)((char*)d_ws + szT + szBins);
    int* perm     = (int*)((char*)d_ws + szT + 2 * szBins);
    hipMemsetAsync(bins, 0, szBins, stream);
    prep_k<<<dim3(NTRB + NHSB), dim3(256), 0, stream>>>(f0, f1, f2, T, x, bins);
    scan_k<<<dim3(1), dim3(256), 0, stream>>>(bins, cursors);
    scatter_k<<<dim3(NHSB), dim3(256), 0, stream>>>(x, cursors, perm);
    sample4_k<<<dim3(2048), dim3(256), 0, stream>>>(x, T, perm, out);
  } else if (ws_size >= szT) {
    float* T = (float*)d_ws;
    prep_k<<<dim3(NTRB), dim3(256), 0, stream>>>(f0, f1, f2, T, x, nullptr);
    sample2_k<<<dim3(4096), dim3(256), 0, stream>>>(x, T, out);
  } else {
    sample_fb_k<<<dim3(8192), dim3(256), 0, stream>>>(x, f0, f1, f2, out);
  }
}

// Round 7
// 137.018 us; speedup vs baseline: 4.7995x; 1.5661x over previous
//
#include <hip/hip_runtime.h>
#include <math.h>

#define P_N 524288
#define NFRAMES 100
#define RESO_ 256
#define CHAN_ 64
#define NFREQ 10

// Transposed layout: T[(f*3+pl)][t][x][c] ; c contiguous
#define TROW   (RESO_ * CHAN_)          // 16384 floats per t-row
#define TPLANE (NFRAMES * TROW)         // 1,638,400 floats per plane

#define NSUBS 64                        // independent sort blocks
#define SUBSZ (P_N / NSUBS)             // 8192 points per sub
#define NTRB  (3 * 3 * NFRAMES * 4)     // 3600 transpose blocks

// ---------------- fused prep: 64 per-sub LDS counting-sorts + transpose ----
// Sort blocks first (latency-heavy, overlap the transpose horde).
template <bool WXS>
__global__ __launch_bounds__(256) void prep2_k(const float* __restrict__ f0,
                                               const float* __restrict__ f1,
                                               const float* __restrict__ f2,
                                               float* __restrict__ T,
                                               const float* __restrict__ xin,
                                               int* __restrict__ perm,
                                               float4* __restrict__ xs4) {
  __shared__ float tile[64][65];
  __shared__ int histS[104];

  if (blockIdx.x < NSUBS) {
    if (perm == nullptr) return;         // transpose-only tier
    const int s = blockIdx.x;
    const float4* __restrict__ x4 = (const float4*)xin;
    for (int i = threadIdx.x; i < 104; i += 256) histS[i] = 0;
    __syncthreads();
    // phase A: histogram of t within this sub
    for (int i = threadIdx.x; i < SUBSZ; i += 256) {
      float tw = x4[(size_t)s * SUBSZ + i].w;
      int t = min(max((int)tw, 0), NFRAMES - 1);
      atomicAdd(&histS[t], 1);
    }
    __syncthreads();
    // phase B: exclusive scan (in-place -> cursors)
    if (threadIdx.x == 0) {
      int run = 0;
      for (int t = 0; t < NFRAMES; t++) { int v = histS[t]; histS[t] = run; run += v; }
    }
    __syncthreads();
    // phase C: scatter perm (+ sorted coords)
    for (int i = threadIdx.x; i < SUBSZ; i += 256) {
      float4 v = x4[(size_t)s * SUBSZ + i];
      int t = min(max((int)v.w, 0), NFRAMES - 1);
      int pos = s * SUBSZ + atomicAdd(&histS[t], 1);
      perm[pos] = s * SUBSZ + i;
      if (WXS) xs4[pos] = v;
    }
    return;
  }

  // ---- transpose blocks ----
  int b = blockIdx.x - NSUBS;
  int xblk = b & 3; b >>= 2;                 // 4 x-tiles of 64
  int t = b % NFRAMES; b /= NFRAMES;
  int pl = b % 3; int f = b / 3;
  const float* src = (f == 0 ? f0 : (f == 1 ? f1 : f2)) + (size_t)pl * CHAN_ * NFRAMES * RESO_;
  int lane = threadIdx.x & 63;
  int w = threadIdx.x >> 6;
  #pragma unroll
  for (int c = 0; c < 16; c++) {
    int cc = w * 16 + c;
    tile[cc][lane] = src[(size_t)cc * (NFRAMES * RESO_) + (size_t)t * RESO_ + xblk * 64 + lane];
  }
  __syncthreads();
  float* dst = T + ((size_t)(f * 3 + pl) * NFRAMES + t) * TROW + (size_t)(xblk * 64) * CHAN_;
  #pragma unroll
  for (int i = 0; i < 16; i++) {
    int xx = w * 16 + i;
    dst[(size_t)xx * CHAN_ + lane] = tile[lane][xx];
  }
}

__device__ __forceinline__ float hw_sin_rev(float rev) {
  float r = rev - floorf(rev);
  float s;
  asm("v_sin_f32 %0, %1" : "=v"(s) : "v"(r));
  return s;
}

// 4 points per wave iteration: lane-group g = lane>>4 owns point k*4+g.
// 16-lane group loads full 64-channel rows as float4 (256 B/row).
// Wave owns 32 consecutive points of its sub's t-sorted order; block->(q,s)
// mapping puts equal within-sub chunk index (~equal t) on the same XCD.
template <bool XS>
__global__ __launch_bounds__(256) void sample4s_k(const float* __restrict__ xin,
                                                  const float4* __restrict__ xs4,
                                                  const float* __restrict__ T,
                                                  const int* __restrict__ perm,
                                                  float* __restrict__ out) {
  const int lane = threadIdx.x & 63;
  const int g = lane >> 4;          // group 0..3
  const int sl = lane & 15;         // sub-lane in group
  const int b = blockIdx.x;         // 4096 blocks
  const int wix = (b >> 3) * 4 + (threadIdx.x >> 6);   // 0..2047 within XCD
  const int q = (b & 7) * 32 + (wix >> 6);             // chunk 0..255 (~t)
  const int s = wix & 63;                              // sub 0..63
  const int base = s * SUBSZ + q * 32;                 // 32 points per wave

  // per-lane PE constants (output element id = lane, valid for lane<63)
  const int j = (lane >= 3) ? (lane - 3) : 0;
  const int fq = j / 6;
  const int rr = j - fq * 6;
  const int isc = rr / 3;
  const int dd = rr - isc * 3;
  const float scale = (float)(1 << fq);
  const float cosoff = isc ? 0.25f : 0.0f;
  const float inv2pi = 0.15915493667125702f;

  const float4* __restrict__ x4 = (const float4*)xin;

  // wave's 32 perm entries in one coalesced load (lanes 0..31 mirrored)
  const int permv = perm[base + (lane & 31)];

  float4 c;
  if (XS) c = xs4[base + g];
  else    c = x4[__shfl(permv, g, 64)];

  #pragma unroll 2
  for (int k = 0; k < 8; k++) {
    // ---- STAGE: weights + all 18 row-gathers + next coord prefetch ----
    float tn = c.w / 99.0f;
    float gy = 2.0f * tn - 1.0f;
    float iy = ((gy + 1.0f) * 0.5f) * 99.0f;
    float y0f = floorf(iy);
    float wy1 = iy - y0f;
    int row; float wy;
    if (wy1 > 0.5f) { row = (int)y0f + 1; wy = wy1; }
    else            { row = (int)y0f;     wy = 1.0f - wy1; }
    row = min(max(row, 0), NFRAMES - 1);
    const int rowoff = row * TROW;

    float wx1v[9];
    float4 v0[9], v1[9];
    float crd[3] = {c.x, c.y, c.z};
    #pragma unroll
    for (int ss = 0; ss < 9; ss++) {
      float gx = 2.0f * crd[ss % 3] - 1.0f;
      float ix = ((gx + 1.0f) * 0.5f) * 255.0f;
      float x0f = floorf(ix);
      wx1v[ss] = ix - x0f;
      int x0 = (int)x0f;                   // coords uniform [0,1) -> 0..254
      const float4* rp = (const float4*)(T + (size_t)ss * TPLANE
                                           + (size_t)(rowoff + x0 * CHAN_));
      v0[ss] = rp[sl];                     // x0 row, channels 4sl..4sl+3
      v1[ss] = rp[sl + 16];                // x0+1 row
    }
    float4 c_nxt = c;
    if (k < 7) {
      if (XS) c_nxt = xs4[base + (k + 1) * 4 + g];
      else    c_nxt = x4[__shfl(permv, (k + 1) * 4 + g, 64)];
    }
    __builtin_amdgcn_sched_barrier(0);     // pin the load batch above

    // ---- CONSUME ----
    float wy3 = wy * wy * wy;
    float dsum[3];
    #pragma unroll
    for (int f = 0; f < 3; f++) {
      float prx, pry, prz, prw;
      #pragma unroll
      for (int pl = 0; pl < 3; pl++) {
        int ss = f * 3 + pl;
        float w1 = wx1v[ss];
        float sx = fmaf(w1, v1[ss].x - v0[ss].x, v0[ss].x);
        float sy = fmaf(w1, v1[ss].y - v0[ss].y, v0[ss].y);
        float sz = fmaf(w1, v1[ss].z - v0[ss].z, v0[ss].z);
        float sw = fmaf(w1, v1[ss].w - v0[ss].w, v0[ss].w);
        if (pl == 0) { prx = sx; pry = sy; prz = sz; prw = sw; }
        else         { prx *= sx; pry *= sy; prz *= sz; prw *= sw; }
      }
      float r = ((prx + pry) + (prz + prw)) * wy3;
      #pragma unroll
      for (int m = 8; m > 0; m >>= 1) r += __shfl_xor(r, m, 64);  // 16-group
      dsum[f] = r;
    }

    float px = c.x + dsum[0];
    float py = c.y + dsum[1];
    float pz = c.z + dsum[2];

    // ---- PE + store: 4 rounds, one point each ----
    #pragma unroll
    for (int q2 = 0; q2 < 4; q2++) {
      float qx = __shfl(px, q2 * 16, 64);
      float qy = __shfl(py, q2 * 16, 64);
      float qz = __shfl(pz, q2 * 16, 64);
      int pq = __shfl(permv, k * 4 + q2, 64);
      float pd = (dd == 0) ? qx : (dd == 1) ? qy : qz;
      float val = hw_sin_rev(pd * scale * inv2pi + cosoff);
      if (lane == 0) val = qx;
      else if (lane == 1) val = qy;
      else if (lane == 2) val = qz;
      if (lane < 63)
        __builtin_nontemporal_store(val, &out[(size_t)pq * 63 + lane]);
    }

    c = c_nxt;
  }
}

// ---- unsorted variant (ws fits T only): 2-pt/wave, float2 channel pairs ----
__global__ __launch_bounds__(256) void sample2_k(const float* __restrict__ xin,
                                                 const float* __restrict__ T,
                                                 float* __restrict__ out) {
  const int lane = threadIdx.x & 63;
  const int half = lane >> 5;
  const int l = lane & 31;
  const int wave = blockIdx.x * 4 + (threadIdx.x >> 6);
  const int nW = gridDim.x * 4;
  const int j = (lane >= 3) ? (lane - 3) : 0;
  const int fq = j / 6;
  const int rr = j - fq * 6;
  const int isc = rr / 3;
  const int dd = rr - isc * 3;
  const float scale = (float)(1 << fq);
  const float cosoff = isc ? 0.25f : 0.0f;
  const float inv2pi = 0.15915493667125702f;
  const float4* __restrict__ x4 = (const float4*)xin;

  for (int base = wave * 2; base < P_N; base += nW * 2) {
    const int p = base + half;
    float4 c = x4[p];
    float tn = c.w / 99.0f;
    float gy = 2.0f * tn - 1.0f;
    float iy = ((gy + 1.0f) * 0.5f) * 99.0f;
    float y0f = floorf(iy);
    float wy1 = iy - y0f;
    int row; float wy;
    if (wy1 > 0.5f) { row = (int)y0f + 1; wy = wy1; }
    else            { row = (int)y0f;     wy = 1.0f - wy1; }
    row = min(max(row, 0), NFRAMES - 1);
    const int rowoff = row * TROW;
    float dsum[3];
    float crd[3] = {c.x, c.y, c.z};
    #pragma unroll
    for (int f = 0; f < 3; f++) {
      float prx, pry;
      #pragma unroll
      for (int pl = 0; pl < 3; pl++) {
        float gx = 2.0f * crd[pl] - 1.0f;
        float ix = ((gx + 1.0f) * 0.5f) * 255.0f;
        float x0f = floorf(ix);
        float wx1 = ix - x0f;
        float wx0 = 1.0f - wx1;
        int x0 = (int)x0f;
        const float2* rp = (const float2*)(T + (size_t)(f * 3 + pl) * TPLANE
                                             + (size_t)(rowoff + x0 * CHAN_));
        float2 v0 = rp[l];
        float2 v1 = rp[l + 32];
        float sx = (v0.x * wx0 + v1.x * wx1) * wy;
        float sy = (v0.y * wx0 + v1.y * wx1) * wy;
        if (pl == 0) { prx = sx; pry = sy; }
        else         { prx *= sx; pry *= sy; }
      }
      float r = prx + pry;
      #pragma unroll
      for (int m = 16; m > 0; m >>= 1) r += __shfl_xor(r, m, 64);
      dsum[f] = r;
    }
    float px = c.x + dsum[0];
    float py = c.y + dsum[1];
    float pz = c.z + dsum[2];
    #pragma unroll
    for (int qq = 0; qq < 2; qq++) {
      float qx = __shfl(px, qq * 32, 64);
      float qy = __shfl(py, qq * 32, 64);
      float qz = __shfl(pz, qq * 32, 64);
      float pd = (dd == 0) ? qx : (dd == 1) ? qy : qz;
      float val = hw_sin_rev(pd * scale * inv2pi + cosoff);
      if (lane == 0) val = qx;
      else if (lane == 1) val = qy;
      else if (lane == 2) val = qz;
      if (lane < 63) out[(size_t)(base + qq) * 63 + lane] = val;
    }
  }
}

// ---- fallback (no usable ws): direct-layout sampler ----
__global__ __launch_bounds__(256) void sample_fb_k(const float* __restrict__ xin,
                                                   const float* __restrict__ f0,
                                                   const float* __restrict__ f1,
                                                   const float* __restrict__ f2,
                                                   float* __restrict__ out) {
  const int lane = threadIdx.x & 63;
  int wave = blockIdx.x * 4 + (threadIdx.x >> 6);
  const int nW = gridDim.x * 4;
  for (int p = wave; p < P_N; p += nW) {
    float cx = xin[(size_t)p * 4 + 0];
    float cy = xin[(size_t)p * 4 + 1];
    float cz = xin[(size_t)p * 4 + 2];
    float ct = xin[(size_t)p * 4 + 3];
    float tn = ct / 99.0f;
    float gy = 2.0f * tn - 1.0f;
    float iy = ((gy + 1.0f) * 0.5f) * 99.0f;
    float y0f = floorf(iy);
    float wy1 = iy - y0f;
    float wy0 = 1.0f - wy1;
    int y0 = (int)y0f, y1 = y0 + 1;
    bool y0in = (unsigned)y0 < (unsigned)NFRAMES;
    bool y1in = (unsigned)y1 < (unsigned)NFRAMES;
    int y0c = min(max(y0, 0), NFRAMES - 1);
    int y1c = min(max(y1, 0), NFRAMES - 1);
    float d[3];
    #pragma unroll
    for (int f = 0; f < 3; f++) {
      float prodc;
      #pragma unroll
      for (int pl = 0; pl < 3; pl++) {
        float coord = (pl == 0) ? cx : (pl == 1) ? cy : cz;
        float gx = 2.0f * coord - 1.0f;
        float ix = ((gx + 1.0f) * 0.5f) * 255.0f;
        float x0f = floorf(ix);
        float wx1 = ix - x0f;
        float wx0 = 1.0f - wx1;
        int x0 = (int)x0f, x1 = x0 + 1;
        int x0c = min(max(x0, 0), RESO_ - 1);
        int x1c = min(max(x1, 0), RESO_ - 1);
        const float* ff = (f == 0) ? f0 : (f == 1) ? f1 : f2;
        const float* bse = ff + ((size_t)pl * CHAN_ + lane) * (NFRAMES * RESO_);
        float v00 = y0in ? bse[(size_t)y0c * RESO_ + x0c] : 0.0f;
        float v01 = y0in ? bse[(size_t)y0c * RESO_ + x1c] : 0.0f;
        float v10 = y1in ? bse[(size_t)y1c * RESO_ + x0c] : 0.0f;
        float v11 = y1in ? bse[(size_t)y1c * RESO_ + x1c] : 0.0f;
        float ss = v00 * (wy0 * wx0) + v01 * (wy0 * wx1) + v10 * (wy1 * wx0) + v11 * (wy1 * wx1);
        prodc = (pl == 0) ? ss : prodc * ss;
      }
      float sum = prodc;
      #pragma unroll
      for (int o = 32; o > 0; o >>= 1) sum += __shfl_xor(sum, o, 64);
      d[f] = sum;
    }
    float p0 = cx + d[0], p1 = cy + d[1], p2 = cz + d[2];
    if (lane < 63) {
      float val;
      if (lane == 0) val = p0;
      else if (lane == 1) val = p1;
      else if (lane == 2) val = p2;
      else {
        int jj = lane - 3;
        int fq2 = jj / 6;
        int r2 = jj - fq2 * 6;
        int s2 = r2 / 3;
        int d2 = r2 - s2 * 3;
        float pd = (d2 == 0) ? p0 : (d2 == 1) ? p1 : p2;
        float ang = pd * (float)(1 << fq2);
        val = (s2 == 0) ? sinf(ang) : cosf(ang);
      }
      out[(size_t)p * 63 + lane] = val;
    }
  }
}

extern "C" void kernel_launch(void* const* d_in, const int* in_sizes, int n_in,
                              void* d_out, int out_size, void* d_ws, size_t ws_size,
                              hipStream_t stream) {
  const float* x  = (const float*)d_in[0];
  const float* f0 = (const float*)d_in[1];
  const float* f1 = (const float*)d_in[2];
  const float* f2 = (const float*)d_in[3];
  float* out = (float*)d_out;

  const size_t szT    = (size_t)9 * TPLANE * sizeof(float);     // ~59 MB
  const size_t szPerm = (size_t)P_N * sizeof(int);              // 2 MB
  const size_t szXs   = (size_t)P_N * sizeof(float4);           // 8 MB

  if (ws_size >= szT + szPerm + szXs) {
    float* T    = (float*)d_ws;
    int* perm   = (int*)((char*)d_ws + szT);
    float4* xs4 = (float4*)((char*)d_ws + szT + szPerm);
    prep2_k<true><<<dim3(NSUBS + NTRB), dim3(256), 0, stream>>>(f0, f1, f2, T, x, perm, xs4);
    sample4s_k<true><<<dim3(4096), dim3(256), 0, stream>>>(x, xs4, T, perm, out);
  } else if (ws_size >= szT + szPerm) {
    float* T  = (float*)d_ws;
    int* perm = (int*)((char*)d_ws + szT);
    prep2_k<false><<<dim3(NSUBS + NTRB), dim3(256), 0, stream>>>(f0, f1, f2, T, x, perm, nullptr);
    sample4s_k<false><<<dim3(4096), dim3(256), 0, stream>>>(x, nullptr, T, perm, out);
  } else if (ws_size >= szT) {
    float* T = (float*)d_ws;
    prep2_k<false><<<dim3(NSUBS + NTRB), dim3(256), 0, stream>>>(f0, f1, f2, T, x, nullptr, nullptr);
    sample2_k<<<dim3(4096), dim3(256), 0, stream>>>(x, T, out);
  } else {
    sample_fb_k<<<dim3(8192), dim3(256), 0, stream>>>(x, f0, f1, f2, out);
  }
}

// Round 8
// 136.796 us; speedup vs baseline: 4.8072x; 1.0016x over previous
//
#include <hip/hip_runtime.h>
#include <math.h>

#define P_N 524288
#define NFRAMES 100
#define RESO_ 256
#define CHAN_ 64
#define NFREQ 10

// Transposed layout: T[(f*3+pl)][t][x][c] ; c contiguous
#define TROW   (RESO_ * CHAN_)          // 16384 floats per t-row
#define TPLANE (NFRAMES * TROW)         // 1,638,400 floats per plane

#define NSUBS 64                        // independent sort blocks
#define SUBSZ (P_N / NSUBS)             // 8192 points per sub
#define NTRB  (3 * 3 * NFRAMES * 4)     // 3600 transpose blocks

// ---------------- fused prep: 64 per-sub LDS counting-sorts + transpose ----
template <bool WXS>
__global__ __launch_bounds__(256) void prep2_k(const float* __restrict__ f0,
                                               const float* __restrict__ f1,
                                               const float* __restrict__ f2,
                                               float* __restrict__ T,
                                               const float* __restrict__ xin,
                                               int* __restrict__ perm,
                                               float4* __restrict__ xs4) {
  __shared__ float tile[64][65];
  __shared__ int histS[104];

  if (blockIdx.x < NSUBS) {
    if (perm == nullptr) return;         // transpose-only tier
    const int s = blockIdx.x;
    const float4* __restrict__ x4 = (const float4*)xin;
    for (int i = threadIdx.x; i < 104; i += 256) histS[i] = 0;
    __syncthreads();
    for (int i = threadIdx.x; i < SUBSZ; i += 256) {
      float tw = x4[(size_t)s * SUBSZ + i].w;
      int t = min(max((int)tw, 0), NFRAMES - 1);
      atomicAdd(&histS[t], 1);
    }
    __syncthreads();
    if (threadIdx.x == 0) {
      int run = 0;
      for (int t = 0; t < NFRAMES; t++) { int v = histS[t]; histS[t] = run; run += v; }
    }
    __syncthreads();
    for (int i = threadIdx.x; i < SUBSZ; i += 256) {
      float4 v = x4[(size_t)s * SUBSZ + i];
      int t = min(max((int)v.w, 0), NFRAMES - 1);
      int pos = s * SUBSZ + atomicAdd(&histS[t], 1);
      perm[pos] = s * SUBSZ + i;
      if (WXS) xs4[pos] = v;
    }
    return;
  }

  // ---- transpose blocks ----
  int b = blockIdx.x - NSUBS;
  int xblk = b & 3; b >>= 2;                 // 4 x-tiles of 64
  int t = b % NFRAMES; b /= NFRAMES;
  int pl = b % 3; int f = b / 3;
  const float* src = (f == 0 ? f0 : (f == 1 ? f1 : f2)) + (size_t)pl * CHAN_ * NFRAMES * RESO_;
  int lane = threadIdx.x & 63;
  int w = threadIdx.x >> 6;
  #pragma unroll
  for (int c = 0; c < 16; c++) {
    int cc = w * 16 + c;
    tile[cc][lane] = src[(size_t)cc * (NFRAMES * RESO_) + (size_t)t * RESO_ + xblk * 64 + lane];
  }
  __syncthreads();
  float* dst = T + ((size_t)(f * 3 + pl) * NFRAMES + t) * TROW + (size_t)(xblk * 64) * CHAN_;
  #pragma unroll
  for (int i = 0; i < 16; i++) {
    int xx = w * 16 + i;
    dst[(size_t)xx * CHAN_ + lane] = tile[lane][xx];
  }
}

__device__ __forceinline__ float hw_sin_rev(float rev) {
  float r, s;
  asm("v_fract_f32 %0, %1" : "=v"(r) : "v"(rev));
  asm("v_sin_f32 %0, %1" : "=v"(s) : "v"(r));
  return s;
}

// STAGE: weights + 3 distinct 32-bit column offsets, issue 18 row loads.
// Byte offset = row*65536 + x0*256 + sl*16; plane bases are SGPR-uniform.
#define STAGEM(V0, V1, WX, WY3, C)                                           \
  {                                                                          \
    float tn = (C).w * (1.0f / 99.0f);                                       \
    float gy = 2.0f * tn - 1.0f;                                             \
    float iy = ((gy + 1.0f) * 0.5f) * 99.0f;                                 \
    float y0f = floorf(iy);                                                  \
    float wy1 = iy - y0f;                                                    \
    int row; float wy;                                                       \
    if (wy1 > 0.5f) { row = (int)y0f + 1; wy = wy1; }                        \
    else            { row = (int)y0f;     wy = 1.0f - wy1; }                 \
    row = min(max(row, 0), NFRAMES - 1);                                     \
    (WY3) = wy * wy * wy;                                                    \
    const unsigned rowbyte = ((unsigned)row << 16) + ((unsigned)sl << 4);    \
    unsigned cb0, cb1, cb2;                                                  \
    { float gx = 2.0f * (C).x - 1.0f; float ix = ((gx + 1.0f) * 0.5f) * 255.0f; \
      float x0f = floorf(ix); (WX)[0] = ix - x0f;                            \
      cb0 = rowbyte + ((unsigned)(int)x0f << 8); }                           \
    { float gx = 2.0f * (C).y - 1.0f; float ix = ((gx + 1.0f) * 0.5f) * 255.0f; \
      float x0f = floorf(ix); (WX)[1] = ix - x0f;                            \
      cb1 = rowbyte + ((unsigned)(int)x0f << 8); }                           \
    { float gx = 2.0f * (C).z - 1.0f; float ix = ((gx + 1.0f) * 0.5f) * 255.0f; \
      float x0f = floorf(ix); (WX)[2] = ix - x0f;                            \
      cb2 = rowbyte + ((unsigned)(int)x0f << 8); }                           \
    _Pragma("unroll")                                                        \
    for (int ss = 0; ss < 9; ss++) {                                         \
      const char* bp = Tb + (size_t)ss * ((size_t)TPLANE * 4);               \
      unsigned cb = (ss % 3 == 0) ? cb0 : (ss % 3 == 1) ? cb1 : cb2;         \
      (V0)[ss] = *(const float4*)(bp + cb);                                  \
      (V1)[ss] = *(const float4*)(bp + cb + 256);                            \
    }                                                                        \
  }

// CONSUME: lerp+product+16-group reduce+PE+store for 4 points (KIDX literal)
#define CONSUMEM(V0, V1, WX, WY3, C, KIDX)                                   \
  {                                                                          \
    float dsum[3];                                                           \
    _Pragma("unroll")                                                        \
    for (int f = 0; f < 3; f++) {                                            \
      float prx, pry, prz, prw;                                              \
      _Pragma("unroll")                                                      \
      for (int pl = 0; pl < 3; pl++) {                                       \
        int ss = f * 3 + pl;                                                 \
        float w1 = (WX)[pl];                                                 \
        float sx = fmaf(w1, (V1)[ss].x - (V0)[ss].x, (V0)[ss].x);            \
        float sy = fmaf(w1, (V1)[ss].y - (V0)[ss].y, (V0)[ss].y);            \
        float sz = fmaf(w1, (V1)[ss].z - (V0)[ss].z, (V0)[ss].z);            \
        float sw = fmaf(w1, (V1)[ss].w - (V0)[ss].w, (V0)[ss].w);            \
        if (pl == 0) { prx = sx; pry = sy; prz = sz; prw = sw; }             \
        else         { prx *= sx; pry *= sy; prz *= sz; prw *= sw; }         \
      }                                                                      \
      float r = ((prx + pry) + (prz + prw)) * (WY3);                         \
      _Pragma("unroll")                                                      \
      for (int m = 8; m > 0; m >>= 1) r += __shfl_xor(r, m, 64);             \
      dsum[f] = r;                                                           \
    }                                                                        \
    float px = (C).x + dsum[0];                                              \
    float py = (C).y + dsum[1];                                              \
    float pz = (C).z + dsum[2];                                              \
    _Pragma("unroll")                                                        \
    for (int q2 = 0; q2 < 4; q2++) {                                         \
      float qx = __shfl(px, q2 * 16, 64);                                    \
      float qy = __shfl(py, q2 * 16, 64);                                    \
      float qz = __shfl(pz, q2 * 16, 64);                                    \
      int pq = __shfl(permv, (KIDX) * 4 + q2, 64);                           \
      float pd = (dd == 0) ? qx : (dd == 1) ? qy : qz;                       \
      float val = hw_sin_rev(pd * scale * inv2pi + cosoff);                  \
      if (lane == 0) val = qx;                                               \
      else if (lane == 1) val = qy;                                          \
      else if (lane == 2) val = qz;                                          \
      if (lane < 63)                                                         \
        __builtin_nontemporal_store(val, &out[(size_t)pq * 63 + lane]);      \
    }                                                                        \
  }

// 4 points/iter, depth-2 fenced register pipeline: B's 18 loads issued
// before consuming A (sched_barrier(0) pins order -> counted vmcnt).
__global__ __launch_bounds__(256, 3) void sample4p_k(const float4* __restrict__ xs4,
                                                     const float* __restrict__ T,
                                                     const int* __restrict__ perm,
                                                     float* __restrict__ out) {
  const int lane = threadIdx.x & 63;
  const int g = lane >> 4;
  const int sl = lane & 15;
  const int b = blockIdx.x;         // 4096 blocks
  const int wix = (b >> 3) * 4 + (threadIdx.x >> 6);   // 0..2047 within XCD
  const int q = (b & 7) * 32 + (wix >> 6);             // chunk 0..255 (~t)
  const int s = wix & 63;                              // sub 0..63
  const int base = s * SUBSZ + q * 32;                 // 32 points per wave

  const int j = (lane >= 3) ? (lane - 3) : 0;
  const int fq = j / 6;
  const int rr = j - fq * 6;
  const int isc = rr / 3;
  const int dd = rr - isc * 3;
  const float scale = (float)(1 << fq);
  const float cosoff = isc ? 0.25f : 0.0f;
  const float inv2pi = 0.15915493667125702f;

  const char* Tb = (const char*)T;
  const int permv = perm[base + (lane & 31)];

  float4 v0A[9], v1A[9], v0B[9], v1B[9];
  float wxA[3], wxB[3], wy3A, wy3B;

  float4 c0 = xs4[base + g];
  float4 c1 = xs4[base + 4 + g];
  STAGEM(v0A, v1A, wxA, wy3A, c0);
  __builtin_amdgcn_sched_barrier(0);

  #pragma unroll 1
  for (int kk = 0; kk < 3; kk++) {
    const int k = kk * 2;
    STAGEM(v0B, v1B, wxB, wy3B, c1);                 // pair k+1 in flight
    float4 c2 = xs4[base + (k + 2) * 4 + g];
    __builtin_amdgcn_sched_barrier(0);
    CONSUMEM(v0A, v1A, wxA, wy3A, c0, k);            // consume k
    __builtin_amdgcn_sched_barrier(0);
    STAGEM(v0A, v1A, wxA, wy3A, c2);                 // pair k+2 in flight
    float4 c3 = xs4[base + (k + 3) * 4 + g];
    __builtin_amdgcn_sched_barrier(0);
    CONSUMEM(v0B, v1B, wxB, wy3B, c1, k + 1);        // consume k+1
    __builtin_amdgcn_sched_barrier(0);
    c0 = c2; c1 = c3;
  }
  // epilogue: k = 6 staged (A), c1 = coords(7)
  STAGEM(v0B, v1B, wxB, wy3B, c1);
  __builtin_amdgcn_sched_barrier(0);
  CONSUMEM(v0A, v1A, wxA, wy3A, c0, 6);
  CONSUMEM(v0B, v1B, wxB, wy3B, c1, 7);
}

// ---- non-pipelined sorted variant (perm but no xs tier) ----
template <bool XS>
__global__ __launch_bounds__(256) void sample4s_k(const float* __restrict__ xin,
                                                  const float4* __restrict__ xs4u,
                                                  const float* __restrict__ T,
                                                  const int* __restrict__ perm,
                                                  float* __restrict__ out) {
  const int lane = threadIdx.x & 63;
  const int g = lane >> 4;
  const int sl = lane & 15;
  const int b = blockIdx.x;
  const int wix = (b >> 3) * 4 + (threadIdx.x >> 6);
  const int q = (b & 7) * 32 + (wix >> 6);
  const int s = wix & 63;
  const int base = s * SUBSZ + q * 32;

  const int j = (lane >= 3) ? (lane - 3) : 0;
  const int fq = j / 6;
  const int rr = j - fq * 6;
  const int isc = rr / 3;
  const int dd = rr - isc * 3;
  const float scale = (float)(1 << fq);
  const float cosoff = isc ? 0.25f : 0.0f;
  const float inv2pi = 0.15915493667125702f;

  const char* Tb = (const char*)T;
  const float4* __restrict__ x4 = (const float4*)xin;
  const int permv = perm[base + (lane & 31)];

  float4 c;
  if (XS) c = xs4u[base + g];
  else    c = x4[__shfl(permv, g, 64)];

  #pragma unroll 2
  for (int k = 0; k < 8; k++) {
    float4 v0[9], v1[9];
    float wx[3], wy3;
    STAGEM(v0, v1, wx, wy3, c);
    float4 c_nxt = c;
    if (k < 7) {
      if (XS) c_nxt = xs4u[base + (k + 1) * 4 + g];
      else    c_nxt = x4[__shfl(permv, (k + 1) * 4 + g, 64)];
    }
    __builtin_amdgcn_sched_barrier(0);
    CONSUMEM(v0, v1, wx, wy3, c, k);
    c = c_nxt;
  }
}

// ---- unsorted variant (ws fits T only): 2-pt/wave, float2 channel pairs ----
__global__ __launch_bounds__(256) void sample2_k(const float* __restrict__ xin,
                                                 const float* __restrict__ T,
                                                 float* __restrict__ out) {
  const int lane = threadIdx.x & 63;
  const int half = lane >> 5;
  const int l = lane & 31;
  const int wave = blockIdx.x * 4 + (threadIdx.x >> 6);
  const int nW = gridDim.x * 4;
  const int j = (lane >= 3) ? (lane - 3) : 0;
  const int fq = j / 6;
  const int rr = j - fq * 6;
  const int isc = rr / 3;
  const int dd = rr - isc * 3;
  const float scale = (float)(1 << fq);
  const float cosoff = isc ? 0.25f : 0.0f;
  const float inv2pi = 0.15915493667125702f;
  const float4* __restrict__ x4 = (const float4*)xin;

  for (int base = wave * 2; base < P_N; base += nW * 2) {
    const int p = base + half;
    float4 c = x4[p];
    float tn = c.w / 99.0f;
    float gy = 2.0f * tn - 1.0f;
    float iy = ((gy + 1.0f) * 0.5f) * 99.0f;
    float y0f = floorf(iy);
    float wy1 = iy - y0f;
    int row; float wy;
    if (wy1 > 0.5f) { row = (int)y0f + 1; wy = wy1; }
    else            { row = (int)y0f;     wy = 1.0f - wy1; }
    row = min(max(row, 0), NFRAMES - 1);
    const int rowoff = row * TROW;
    float dsum[3];
    float crd[3] = {c.x, c.y, c.z};
    #pragma unroll
    for (int f = 0; f < 3; f++) {
      float prx, pry;
      #pragma unroll
      for (int pl = 0; pl < 3; pl++) {
        float gx = 2.0f * crd[pl] - 1.0f;
        float ix = ((gx + 1.0f) * 0.5f) * 255.0f;
        float x0f = floorf(ix);
        float wx1 = ix - x0f;
        float wx0 = 1.0f - wx1;
        int x0 = (int)x0f;
        const float2* rp = (const float2*)(T + (size_t)(f * 3 + pl) * TPLANE
                                             + (size_t)(rowoff + x0 * CHAN_));
        float2 v0 = rp[l];
        float2 v1 = rp[l + 32];
        float sx = (v0.x * wx0 + v1.x * wx1) * wy;
        float sy = (v0.y * wx0 + v1.y * wx1) * wy;
        if (pl == 0) { prx = sx; pry = sy; }
        else         { prx *= sx; pry *= sy; }
      }
      float r = prx + pry;
      #pragma unroll
      for (int m = 16; m > 0; m >>= 1) r += __shfl_xor(r, m, 64);
      dsum[f] = r;
    }
    float px = c.x + dsum[0];
    float py = c.y + dsum[1];
    float pz = c.z + dsum[2];
    #pragma unroll
    for (int qq = 0; qq < 2; qq++) {
      float qx = __shfl(px, qq * 32, 64);
      float qy = __shfl(py, qq * 32, 64);
      float qz = __shfl(pz, qq * 32, 64);
      float pd = (dd == 0) ? qx : (dd == 1) ? qy : qz;
      float val = hw_sin_rev(pd * scale * inv2pi + cosoff);
      if (lane == 0) val = qx;
      else if (lane == 1) val = qy;
      else if (lane == 2) val = qz;
      if (lane < 63) out[(size_t)(base + qq) * 63 + lane] = val;
    }
  }
}

// ---- fallback (no usable ws): direct-layout sampler ----
__global__ __launch_bounds__(256) void sample_fb_k(const float* __restrict__ xin,
                                                   const float* __restrict__ f0,
                                                   const float* __restrict__ f1,
                                                   const float* __restrict__ f2,
                                                   float* __restrict__ out) {
  const int lane = threadIdx.x & 63;
  int wave = blockIdx.x * 4 + (threadIdx.x >> 6);
  const int nW = gridDim.x * 4;
  for (int p = wave; p < P_N; p += nW) {
    float cx = xin[(size_t)p * 4 + 0];
    float cy = xin[(size_t)p * 4 + 1];
    float cz = xin[(size_t)p * 4 + 2];
    float ct = xin[(size_t)p * 4 + 3];
    float tn = ct / 99.0f;
    float gy = 2.0f * tn - 1.0f;
    float iy = ((gy + 1.0f) * 0.5f) * 99.0f;
    float y0f = floorf(iy);
    float wy1 = iy - y0f;
    float wy0 = 1.0f - wy1;
    int y0 = (int)y0f, y1 = y0 + 1;
    bool y0in = (unsigned)y0 < (unsigned)NFRAMES;
    bool y1in = (unsigned)y1 < (unsigned)NFRAMES;
    int y0c = min(max(y0, 0), NFRAMES - 1);
    int y1c = min(max(y1, 0), NFRAMES - 1);
    float d[3];
    #pragma unroll
    for (int f = 0; f < 3; f++) {
      float prodc;
      #pragma unroll
      for (int pl = 0; pl < 3; pl++) {
        float coord = (pl == 0) ? cx : (pl == 1) ? cy : cz;
        float gx = 2.0f * coord - 1.0f;
        float ix = ((gx + 1.0f) * 0.5f) * 255.0f;
        float x0f = floorf(ix);
        float wx1 = ix - x0f;
        float wx0 = 1.0f - wx1;
        int x0 = (int)x0f, x1 = x0 + 1;
        int x0c = min(max(x0, 0), RESO_ - 1);
        int x1c = min(max(x1, 0), RESO_ - 1);
        const float* ff = (f == 0) ? f0 : (f == 1) ? f1 : f2;
        const float* bse = ff + ((size_t)pl * CHAN_ + lane) * (NFRAMES * RESO_);
        float v00 = y0in ? bse[(size_t)y0c * RESO_ + x0c] : 0.0f;
        float v01 = y0in ? bse[(size_t)y0c * RESO_ + x1c] : 0.0f;
        float v10 = y1in ? bse[(size_t)y1c * RESO_ + x0c] : 0.0f;
        float v11 = y1in ? bse[(size_t)y1c * RESO_ + x1c] : 0.0f;
        float ss2 = v00 * (wy0 * wx0) + v01 * (wy0 * wx1) + v10 * (wy1 * wx0) + v11 * (wy1 * wx1);
        prodc = (pl == 0) ? ss2 : prodc * ss2;
      }
      float sum = prodc;
      #pragma unroll
      for (int o = 32; o > 0; o >>= 1) sum += __shfl_xor(sum, o, 64);
      d[f] = sum;
    }
    float p0 = cx + d[0], p1 = cy + d[1], p2 = cz + d[2];
    if (lane < 63) {
      float val;
      if (lane == 0) val = p0;
      else if (lane == 1) val = p1;
      else if (lane == 2) val = p2;
      else {
        int jj = lane - 3;
        int fq2 = jj / 6;
        int r2 = jj - fq2 * 6;
        int s2 = r2 / 3;
        int d2 = r2 - s2 * 3;
        float pd = (d2 == 0) ? p0 : (d2 == 1) ? p1 : p2;
        float ang = pd * (float)(1 << fq2);
        val = (s2 == 0) ? sinf(ang) : cosf(ang);
      }
      out[(size_t)p * 63 + lane] = val;
    }
  }
}

extern "C" void kernel_launch(void* const* d_in, const int* in_sizes, int n_in,
                              void* d_out, int out_size, void* d_ws, size_t ws_size,
                              hipStream_t stream) {
  const float* x  = (const float*)d_in[0];
  const float* f0 = (const float*)d_in[1];
  const float* f1 = (const float*)d_in[2];
  const float* f2 = (const float*)d_in[3];
  float* out = (float*)d_out;

  const size_t szT    = (size_t)9 * TPLANE * sizeof(float);     // ~59 MB
  const size_t szPerm = (size_t)P_N * sizeof(int);              // 2 MB
  const size_t szXs   = (size_t)P_N * sizeof(float4);           // 8 MB

  if (ws_size >= szT + szPerm + szXs) {
    float* T    = (float*)d_ws;
    int* perm   = (int*)((char*)d_ws + szT);
    float4* xs4 = (float4*)((char*)d_ws + szT + szPerm);
    prep2_k<true><<<dim3(NSUBS + NTRB), dim3(256), 0, stream>>>(f0, f1, f2, T, x, perm, xs4);
    sample4p_k<<<dim3(4096), dim3(256), 0, stream>>>(xs4, T, perm, out);
  } else if (ws_size >= szT + szPerm) {
    float* T  = (float*)d_ws;
    int* perm = (int*)((char*)d_ws + szT);
    prep2_k<false><<<dim3(NSUBS + NTRB), dim3(256), 0, stream>>>(f0, f1, f2, T, x, perm, nullptr);
    sample4s_k<false><<<dim3(4096), dim3(256), 0, stream>>>(x, nullptr, T, perm, out);
  } else if (ws_size >= szT) {
    float* T = (float*)d_ws;
    prep2_k<false><<<dim3(NSUBS + NTRB), dim3(256), 0, stream>>>(f0, f1, f2, T, x, nullptr, nullptr);
    sample2_k<<<dim3(4096), dim3(256), 0, stream>>>(x, T, out);
  } else {
    sample_fb_k<<<dim3(8192), dim3(256), 0, stream>>>(x, f0, f1, f2, out);
  }
}